// Round 4
// baseline (593.674 us; speedup 1.0000x reference)
//
#include <hip/hip_runtime.h>

#define NN 80000
#define NE 1280000
#define NG 2000
#define HID 64
#define FIN1 40
#define SCHUNK 512
#define SNB ((NN + SCHUNK - 1) / SCHUNK)   // 157 blocks
constexpr float EPS = 1e-5f;

// ---------------- embed: x0[n][f] = concat(shape_tab, color_tab, pos_tab) ----
__global__ void embed_kernel(const int* __restrict__ sid, const int* __restrict__ cid,
                             const int* __restrict__ pid,
                             const float* __restrict__ stab, const float* __restrict__ ctab,
                             const float* __restrict__ ptab,
                             float* __restrict__ x0) {
    int idx = blockIdx.x * blockDim.x + threadIdx.x;
    if (idx >= NN * FIN1) return;
    int n = idx / FIN1;
    int f = idx - n * FIN1;
    float v;
    if (f < 16)      v = stab[sid[n] * 16 + f];
    else if (f < 32) v = ctab[cid[n] * 16 + (f - 16)];
    else             v = ptab[pid[n] * 8 + (f - 32)];
    x0[idx] = v;
}

// ---------------- CSR build ----------------
__global__ void deg_hist(const int* __restrict__ dst, int* __restrict__ cursor) {
    int e = blockIdx.x * blockDim.x + threadIdx.x;
    if (e >= NE) return;
    atomicAdd(&cursor[dst[e]], 1);
}

__global__ void scan_a(const int* __restrict__ cursor, int* __restrict__ bsum) {
    __shared__ int l[SCHUNK];
    int t = threadIdx.x;
    int idx = blockIdx.x * SCHUNK + t;
    l[t] = (idx < NN) ? cursor[idx] : 0;
    __syncthreads();
    for (int off = SCHUNK / 2; off >= 1; off >>= 1) {
        if (t < off) l[t] += l[t + off];
        __syncthreads();
    }
    if (t == 0) bsum[blockIdx.x] = l[0];
}

__global__ void scan_b(const int* __restrict__ bsum, int* __restrict__ boffs) {
    __shared__ int l[256];
    int t = threadIdx.x;
    l[t] = (t < SNB) ? bsum[t] : 0;
    __syncthreads();
    for (int off = 1; off < 256; off <<= 1) {
        int v = (t >= off) ? l[t - off] : 0;
        __syncthreads();
        l[t] += v;
        __syncthreads();
    }
    boffs[t] = (t == 0) ? 0 : l[t - 1];
}

__global__ void scan_c(int* __restrict__ cursor, const int* __restrict__ boffs,
                       int* __restrict__ row_ptr) {
    __shared__ int l[SCHUNK];
    int t = threadIdx.x;
    int idx = blockIdx.x * SCHUNK + t;
    l[t] = (idx < NN) ? cursor[idx] : 0;
    __syncthreads();
    for (int off = 1; off < SCHUNK; off <<= 1) {
        int v = (t >= off) ? l[t - off] : 0;
        __syncthreads();
        l[t] += v;
        __syncthreads();
    }
    int excl = ((t == 0) ? 0 : l[t - 1]) + boffs[blockIdx.x];
    if (idx < NN) {
        row_ptr[idx] = excl;
        cursor[idx] = excl;
    }
    if (idx == 0) row_ptr[NN] = NE;
}

__global__ void csr_fill(const int* __restrict__ src, const int* __restrict__ dst,
                         int* __restrict__ cursor, int* __restrict__ eidx) {
    int e = blockIdx.x * blockDim.x + threadIdx.x;
    if (e >= NE) return;
    int pos = atomicAdd(&cursor[dst[e]], 1);
    eidx[pos] = src[e];
}

// ---------------- fused SAGE layer: gather-mean + dual linear ----------------
// one wave per node (grid-stride). lane = feature (gather) / output j (linear).
// W staged in LDS once per block; xa/xr rows via per-wave LDS strip.
template <int FIN>
__launch_bounds__(256)
__global__ void fused_sage(const int* __restrict__ row_ptr, const int* __restrict__ eidx,
                           const float* __restrict__ x,
                           const float* __restrict__ Wl, const float* __restrict__ Wr,
                           const float* __restrict__ b, float* __restrict__ h,
                           int num_waves) {
    __shared__ float wl_s[FIN * HID];
    __shared__ float wr_s[FIN * HID];
    __shared__ float rows[4][2][HID];

    int tid = threadIdx.x;
    // stage Wl, Wr (float4)
    for (int i = tid; i < FIN * HID / 4; i += 256) {
        ((float4*)wl_s)[i] = ((const float4*)Wl)[i];
        ((float4*)wr_s)[i] = ((const float4*)Wr)[i];
    }
    __syncthreads();

    int wv = tid >> 6;
    int lane = tid & 63;
    int wave_id = blockIdx.x * 4 + wv;

    for (int n = wave_id; n < NN; n += num_waves) {
        int beg = row_ptr[n];
        int end = row_ptr[n + 1];
        // ---- gather: acc = sum over neighbors of x[s][lane] ----
        float acc = 0.0f;
        for (int j0 = beg; j0 < end; j0 += 64) {
            int cnt = min(64, end - j0);
            int myid = (j0 + lane < end) ? eidx[j0 + lane] : 0;
            for (int u = 0; u < cnt; u++) {
                int s = __shfl(myid, u);
                if (lane < FIN) acc += x[(size_t)s * FIN + lane];
            }
        }
        float inv = 1.0f / (float)max(end - beg, 1);
        if (lane < FIN) {
            rows[wv][0][lane] = acc * inv;                    // xa
            rows[wv][1][lane] = x[(size_t)n * FIN + lane];    // xr
        }
        // wave-private LDS: compiler inserts lgkmcnt wait; no __syncthreads needed
        __builtin_amdgcn_wave_barrier();

        // ---- linear: h[n][j] = b[j] + sum_k xa[k]*Wl[k][j] + xr[k]*Wr[k][j] ----
        int j = lane;
        float o = b[j];
#pragma unroll 4
        for (int k = 0; k < FIN; k++) {
            float xak = rows[wv][0][k];
            float xrk = rows[wv][1][k];
            o = fmaf(xak, wl_s[k * HID + j], fmaf(xrk, wr_s[k * HID + j], o));
        }
        h[(size_t)n * HID + j] = o;
    }
}

// ---------------- BN stats: stats[f] = sum, stats[64+f] = sumsq -------------
__global__ void bn_stats(const float* __restrict__ h, float* __restrict__ stats) {
    const int NPB = 512;
    int f = threadIdx.x & 63;
    int r = threadIdx.x >> 6;
    int n0 = blockIdx.x * NPB;
    int nend = min(n0 + NPB, NN);
    float s = 0.f, ss = 0.f;
    for (int n = n0 + r; n < nend; n += 4) {
        float v = h[n * HID + f];
        s += v;
        ss += v * v;
    }
    __shared__ float ls[4][64];
    __shared__ float lss[4][64];
    ls[r][f] = s;
    lss[r][f] = ss;
    __syncthreads();
    if (r == 0) {
        s = ls[0][f] + ls[1][f] + ls[2][f] + ls[3][f];
        ss = lss[0][f] + lss[1][f] + lss[2][f] + lss[3][f];
        atomicAdd(&stats[f], s);
        atomicAdd(&stats[64 + f], ss);
    }
}

// ---------------- BN apply + ReLU (layer 1 only) ----------------
__global__ void bn_apply_relu(const float* __restrict__ h, const float* __restrict__ stats,
                              const float* __restrict__ g, const float* __restrict__ be,
                              float* __restrict__ x) {
    int idx = blockIdx.x * blockDim.x + threadIdx.x;
    if (idx >= NN * HID) return;
    int f = idx & 63;
    const float invn = 1.0f / (float)NN;
    float m = stats[f] * invn;
    float var = stats[64 + f] * invn - m * m;
    float sc = g[f] / sqrtf(var + EPS);
    float v = (h[idx] - m) * sc + be[f];
    x[idx] = fmaxf(v, 0.0f);
}

// ---------------- graph boundaries from sorted batch ----------------
__global__ void graph_bounds(const int* __restrict__ batch, int* __restrict__ gstart) {
    int n = blockIdx.x * blockDim.x + threadIdx.x;
    if (n >= NN) return;
    int cur = batch[n];
    int prev = (n == 0) ? -1 : batch[n - 1];
    for (int g = prev + 1; g <= cur; g++) gstart[g] = n;
    if (n == NN - 1) {
        for (int g = cur + 1; g <= NG; g++) gstart[g] = NN;
    }
}

// ---------------- fused layer2-BN+ReLU + mean-pool + output GEMV ------------
__global__ void pool_out(const float* __restrict__ h, const float* __restrict__ stats2,
                         const float* __restrict__ g2, const float* __restrict__ be2,
                         const int* __restrict__ gstart,
                         const float* __restrict__ Wout, const float* __restrict__ bout,
                         float* __restrict__ out) {
    int w = (blockIdx.x * blockDim.x + threadIdx.x) >> 6;
    int f = threadIdx.x & 63;
    if (w >= NG) return;
    const float invn = 1.0f / (float)NN;
    float m = stats2[f] * invn;
    float var = stats2[64 + f] * invn - m * m;
    float sc = g2[f] / sqrtf(var + EPS);
    float bb = be2[f];
    int n0 = gstart[w], n1 = gstart[w + 1];
    float acc = 0.f;
    for (int n = n0; n < n1; n++) {
        float v = (h[(size_t)n * HID + f] - m) * sc + bb;
        acc += fmaxf(v, 0.0f);
    }
    float inv = 1.0f / (float)max(n1 - n0, 1);
    float p = acc * inv;
    float a0 = p * Wout[f * 2 + 0];
    float a1 = p * Wout[f * 2 + 1];
#pragma unroll
    for (int mm = 1; mm < 64; mm <<= 1) {
        a0 += __shfl_xor(a0, mm);
        a1 += __shfl_xor(a1, mm);
    }
    if (f == 0) {
        out[w * 2 + 0] = a0 + bout[0];
        out[w * 2 + 1] = a1 + bout[1];
    }
}

extern "C" void kernel_launch(void* const* d_in, const int* in_sizes, int n_in,
                              void* d_out, int out_size, void* d_ws, size_t ws_size,
                              hipStream_t stream) {
    const int* sid = (const int*)d_in[0];
    const int* cid = (const int*)d_in[1];
    const int* pid = (const int*)d_in[2];
    const int* ei = (const int*)d_in[3];
    const int* batch = (const int*)d_in[4];
    const float* stab = (const float*)d_in[6];
    const float* ctab = (const float*)d_in[7];
    const float* ptab = (const float*)d_in[8];
    const float* W1l = (const float*)d_in[9];
    const float* b1 = (const float*)d_in[10];
    const float* W1r = (const float*)d_in[11];
    const float* g1 = (const float*)d_in[12];
    const float* be1 = (const float*)d_in[13];
    const float* W2l = (const float*)d_in[14];
    const float* b2 = (const float*)d_in[15];
    const float* W2r = (const float*)d_in[16];
    const float* g2 = (const float*)d_in[17];
    const float* be2 = (const float*)d_in[18];
    const float* Wout = (const float*)d_in[19];
    const float* bout = (const float*)d_in[20];

    const int* src = ei;
    const int* dst = ei + NE;

    float* ws = (float*)d_ws;
    float* x0 = ws;                                // NN*40 f
    float* hbuf = x0 + (size_t)NN * FIN1;          // NN*64 f (layer1 out / layer2 in)
    float* h2 = hbuf + (size_t)NN * HID;           // NN*64 f (layer2 out)
    float* stats = h2 + (size_t)NN * HID;          // 256 f (both layers)
    int* row_ptr = (int*)(stats + 256);            // NN+1 i
    int* cursor = row_ptr + NN + 1;                // NN i
    int* bsum = cursor + NN;                       // 256 i
    int* boffs = bsum + 256;                       // 256 i
    int* gstart = boffs + 256;                     // NG+1 i
    int* eidx = gstart + NG + 1;                   // NE i

    hipMemsetAsync(cursor, 0, NN * sizeof(int), stream);
    hipMemsetAsync(stats, 0, 256 * sizeof(float), stream);

    const int B = 256;
    const int NBLK = 1024;             // 4096 waves, ~20 nodes each
    const int NWAVES = NBLK * 4;

    // features
    embed_kernel<<<(NN * FIN1 + B - 1) / B, B, 0, stream>>>(sid, cid, pid, stab, ctab, ptab, x0);

    // CSR build (shared across both layers)
    deg_hist<<<(NE + B - 1) / B, B, 0, stream>>>(dst, cursor);
    scan_a<<<SNB, SCHUNK, 0, stream>>>(cursor, bsum);
    scan_b<<<1, 256, 0, stream>>>(bsum, boffs);
    scan_c<<<SNB, SCHUNK, 0, stream>>>(cursor, boffs, row_ptr);
    csr_fill<<<(NE + B - 1) / B, B, 0, stream>>>(src, dst, cursor, eidx);

    // graph boundaries (independent; any time before pool_out)
    graph_bounds<<<(NN + B - 1) / B, B, 0, stream>>>(batch, gstart);

    // ---- layer 1: fused gather+linear ----
    fused_sage<FIN1><<<NBLK, B, 0, stream>>>(row_ptr, eidx, x0, W1l, W1r, b1, hbuf, NWAVES);
    bn_stats<<<(NN + 511) / 512, B, 0, stream>>>(hbuf, stats);
    bn_apply_relu<<<(NN * HID + B - 1) / B, B, 0, stream>>>(hbuf, stats, g1, be1, hbuf);

    // ---- layer 2: fused gather+linear ----
    fused_sage<HID><<<NBLK, B, 0, stream>>>(row_ptr, eidx, hbuf, W2l, W2r, b2, h2, NWAVES);
    bn_stats<<<(NN + 511) / 512, B, 0, stream>>>(h2, stats + 128);

    // ---- fused BN2+ReLU+pool+head ----
    pool_out<<<(NG * 64 + B - 1) / B, B, 0, stream>>>(h2, stats + 128, g2, be2, gstart,
                                                      Wout, bout, (float*)d_out);
}

// Round 5
// 494.364 us; speedup vs baseline: 1.2009x; 1.2009x over previous
//
#include <hip/hip_runtime.h>

#define NN 80000
#define NE 1280000
#define NG 2000
#define HID 64
#define FIN1 40
#define SCHUNK 512
#define SNB ((NN + SCHUNK - 1) / SCHUNK)   // 157 blocks
constexpr float EPS = 1e-5f;

// ---------------- embed: x0[n][f] = concat(shape_tab, color_tab, pos_tab) ----
__global__ void embed_kernel(const int* __restrict__ sid, const int* __restrict__ cid,
                             const int* __restrict__ pid,
                             const float* __restrict__ stab, const float* __restrict__ ctab,
                             const float* __restrict__ ptab,
                             float* __restrict__ x0) {
    int idx = blockIdx.x * blockDim.x + threadIdx.x;
    if (idx >= NN * FIN1) return;
    int n = idx / FIN1;
    int f = idx - n * FIN1;
    float v;
    if (f < 16)      v = stab[sid[n] * 16 + f];
    else if (f < 32) v = ctab[cid[n] * 16 + (f - 16)];
    else             v = ptab[pid[n] * 8 + (f - 32)];
    x0[idx] = v;
}

// ---------------- CSR build ----------------
__global__ void deg_hist(const int* __restrict__ dst, int* __restrict__ cursor) {
    int e = blockIdx.x * blockDim.x + threadIdx.x;
    if (e >= NE) return;
    atomicAdd(&cursor[dst[e]], 1);
}

__global__ void scan_a(const int* __restrict__ cursor, int* __restrict__ bsum) {
    __shared__ int l[SCHUNK];
    int t = threadIdx.x;
    int idx = blockIdx.x * SCHUNK + t;
    l[t] = (idx < NN) ? cursor[idx] : 0;
    __syncthreads();
    for (int off = SCHUNK / 2; off >= 1; off >>= 1) {
        if (t < off) l[t] += l[t + off];
        __syncthreads();
    }
    if (t == 0) bsum[blockIdx.x] = l[0];
}

__global__ void scan_b(const int* __restrict__ bsum, int* __restrict__ boffs) {
    __shared__ int l[256];
    int t = threadIdx.x;
    l[t] = (t < SNB) ? bsum[t] : 0;
    __syncthreads();
    for (int off = 1; off < 256; off <<= 1) {
        int v = (t >= off) ? l[t - off] : 0;
        __syncthreads();
        l[t] += v;
        __syncthreads();
    }
    boffs[t] = (t == 0) ? 0 : l[t - 1];
}

__global__ void scan_c(int* __restrict__ cursor, const int* __restrict__ boffs,
                       int* __restrict__ row_ptr) {
    __shared__ int l[SCHUNK];
    int t = threadIdx.x;
    int idx = blockIdx.x * SCHUNK + t;
    l[t] = (idx < NN) ? cursor[idx] : 0;
    __syncthreads();
    for (int off = 1; off < SCHUNK; off <<= 1) {
        int v = (t >= off) ? l[t - off] : 0;
        __syncthreads();
        l[t] += v;
        __syncthreads();
    }
    int excl = ((t == 0) ? 0 : l[t - 1]) + boffs[blockIdx.x];
    if (idx < NN) {
        row_ptr[idx] = excl;
        cursor[idx] = excl;
    }
    if (idx == 0) row_ptr[NN] = NE;
}

__global__ void csr_fill(const int* __restrict__ src, const int* __restrict__ dst,
                         int* __restrict__ cursor, int* __restrict__ eidx) {
    int e = blockIdx.x * blockDim.x + threadIdx.x;
    if (e >= NE) return;
    int pos = atomicAdd(&cursor[dst[e]], 1);
    eidx[pos] = src[e];
}

// ---------------- gather-aggregate: agg[n][f] = sum_{s in N(n)} x[s][f] -----
// one wave per node; 4 groups of 16 lanes; each group processes one edge with
// float4 row loads -> 4x memory parallelism
template <int F>
__global__ void gather_agg(const int* __restrict__ row_ptr, const int* __restrict__ eidx,
                           const float* __restrict__ x, float* __restrict__ agg) {
    int t = blockIdx.x * blockDim.x + threadIdx.x;
    int n = t >> 6;
    int lane = threadIdx.x & 63;
    if (n >= NN) return;
    int g = lane >> 4;          // group 0..3
    int fl = (lane & 15) * 4;   // feature base for this lane
    int beg = row_ptr[n];
    int end = row_ptr[n + 1];
    float4 acc = make_float4(0.f, 0.f, 0.f, 0.f);
    for (int j0 = beg; j0 < end; j0 += 64) {
        int cnt = min(64, end - j0);
        int myid = (j0 + lane < end) ? eidx[j0 + lane] : 0;
        int steps = (cnt + 3) >> 2;
        for (int u = 0; u < steps; u++) {
            int e = u * 4 + g;
            int s = __shfl(myid, e);
            if (e < cnt && fl < F) {
                const float4 v = *(const float4*)&x[(size_t)s * F + fl];
                acc.x += v.x; acc.y += v.y; acc.z += v.z; acc.w += v.w;
            }
        }
    }
#pragma unroll
    for (int m = 16; m <= 32; m <<= 1) {
        acc.x += __shfl_xor(acc.x, m);
        acc.y += __shfl_xor(acc.y, m);
        acc.z += __shfl_xor(acc.z, m);
        acc.w += __shfl_xor(acc.w, m);
    }
    if (lane < 16 && fl < F) {
        *(float4*)&agg[(size_t)n * F + fl] = acc;
    }
}

// ---------------- linear: h = (agg/deg) @ Wl + b + x @ Wr ----------------
// block = 16 nodes; thread = (node r = tid>>4, j-quad jq = tid&15); float4 acc.
// xa (pre-divided) and xr staged in LDS; W from global (L1/L2-hot).
template <int FIN>
__launch_bounds__(256)
__global__ void linear16(const float* __restrict__ x, const float* __restrict__ agg,
                         const int* __restrict__ row_ptr,
                         const float* __restrict__ Wl, const float* __restrict__ Wr,
                         const float* __restrict__ b, float* __restrict__ h) {
    __shared__ float sxa[16 * FIN];
    __shared__ float sxr[16 * FIN];
    __shared__ float sinv[16];

    int tid = threadIdx.x;
    int n0 = blockIdx.x * 16;

    if (tid < 16) {
        int n = n0 + tid;
        int deg = (n < NN) ? (row_ptr[n + 1] - row_ptr[n]) : 1;
        sinv[tid] = 1.0f / (float)max(deg, 1);
    }
    __syncthreads();
    // stage xa (divided by deg) and xr; the 16 rows are contiguous in memory
    int limit = min(16, NN - n0) * FIN;
    for (int i = tid; i < limit; i += 256) {
        int r = i / FIN;
        sxa[i] = agg[(size_t)n0 * FIN + i] * sinv[r];
        sxr[i] = x[(size_t)n0 * FIN + i];
    }
    __syncthreads();

    int r = tid >> 4;
    int j = (tid & 15) * 4;
    int n = n0 + r;
    if (n >= NN) return;

    float4 acc = *(const float4*)&b[j];
#pragma unroll 8
    for (int k = 0; k < FIN; k++) {
        float xa = sxa[r * FIN + k];
        float xr = sxr[r * FIN + k];
        const float4 wl = *(const float4*)&Wl[k * HID + j];
        const float4 wr = *(const float4*)&Wr[k * HID + j];
        acc.x = fmaf(xa, wl.x, fmaf(xr, wr.x, acc.x));
        acc.y = fmaf(xa, wl.y, fmaf(xr, wr.y, acc.y));
        acc.z = fmaf(xa, wl.z, fmaf(xr, wr.z, acc.z));
        acc.w = fmaf(xa, wl.w, fmaf(xr, wr.w, acc.w));
    }
    *(float4*)&h[(size_t)n * HID + j] = acc;
}

// ---------------- BN stats: stats[f] = sum, stats[64+f] = sumsq -------------
__global__ void bn_stats(const float* __restrict__ h, float* __restrict__ stats) {
    const int NPB = 512;
    int f = threadIdx.x & 63;
    int r = threadIdx.x >> 6;
    int n0 = blockIdx.x * NPB;
    int nend = min(n0 + NPB, NN);
    float s = 0.f, ss = 0.f;
    for (int n = n0 + r; n < nend; n += 4) {
        float v = h[n * HID + f];
        s += v;
        ss += v * v;
    }
    __shared__ float ls[4][64];
    __shared__ float lss[4][64];
    ls[r][f] = s;
    lss[r][f] = ss;
    __syncthreads();
    if (r == 0) {
        s = ls[0][f] + ls[1][f] + ls[2][f] + ls[3][f];
        ss = lss[0][f] + lss[1][f] + lss[2][f] + lss[3][f];
        atomicAdd(&stats[f], s);
        atomicAdd(&stats[64 + f], ss);
    }
}

// ---------------- BN apply + ReLU (layer 1 only) ----------------
__global__ void bn_apply_relu(const float* __restrict__ h, const float* __restrict__ stats,
                              const float* __restrict__ g, const float* __restrict__ be,
                              float* __restrict__ x) {
    int idx = blockIdx.x * blockDim.x + threadIdx.x;
    if (idx >= NN * HID) return;
    int f = idx & 63;
    const float invn = 1.0f / (float)NN;
    float m = stats[f] * invn;
    float var = stats[64 + f] * invn - m * m;
    float sc = g[f] / sqrtf(var + EPS);
    float v = (h[idx] - m) * sc + be[f];
    x[idx] = fmaxf(v, 0.0f);
}

// ---------------- graph boundaries from sorted batch ----------------
__global__ void graph_bounds(const int* __restrict__ batch, int* __restrict__ gstart) {
    int n = blockIdx.x * blockDim.x + threadIdx.x;
    if (n >= NN) return;
    int cur = batch[n];
    int prev = (n == 0) ? -1 : batch[n - 1];
    for (int g = prev + 1; g <= cur; g++) gstart[g] = n;
    if (n == NN - 1) {
        for (int g = cur + 1; g <= NG; g++) gstart[g] = NN;
    }
}

// ---------------- fused layer2-BN+ReLU + mean-pool + output GEMV ------------
__global__ void pool_out(const float* __restrict__ h, const float* __restrict__ stats2,
                         const float* __restrict__ g2, const float* __restrict__ be2,
                         const int* __restrict__ gstart,
                         const float* __restrict__ Wout, const float* __restrict__ bout,
                         float* __restrict__ out) {
    int w = (blockIdx.x * blockDim.x + threadIdx.x) >> 6;
    int f = threadIdx.x & 63;
    if (w >= NG) return;
    const float invn = 1.0f / (float)NN;
    float m = stats2[f] * invn;
    float var = stats2[64 + f] * invn - m * m;
    float sc = g2[f] / sqrtf(var + EPS);
    float bb = be2[f];
    int n0 = gstart[w], n1 = gstart[w + 1];
    float acc = 0.f;
    for (int n = n0; n < n1; n++) {
        float v = (h[(size_t)n * HID + f] - m) * sc + bb;
        acc += fmaxf(v, 0.0f);
    }
    float inv = 1.0f / (float)max(n1 - n0, 1);
    float p = acc * inv;
    float a0 = p * Wout[f * 2 + 0];
    float a1 = p * Wout[f * 2 + 1];
#pragma unroll
    for (int mm = 1; mm < 64; mm <<= 1) {
        a0 += __shfl_xor(a0, mm);
        a1 += __shfl_xor(a1, mm);
    }
    if (f == 0) {
        out[w * 2 + 0] = a0 + bout[0];
        out[w * 2 + 1] = a1 + bout[1];
    }
}

extern "C" void kernel_launch(void* const* d_in, const int* in_sizes, int n_in,
                              void* d_out, int out_size, void* d_ws, size_t ws_size,
                              hipStream_t stream) {
    const int* sid = (const int*)d_in[0];
    const int* cid = (const int*)d_in[1];
    const int* pid = (const int*)d_in[2];
    const int* ei = (const int*)d_in[3];
    const int* batch = (const int*)d_in[4];
    const float* stab = (const float*)d_in[6];
    const float* ctab = (const float*)d_in[7];
    const float* ptab = (const float*)d_in[8];
    const float* W1l = (const float*)d_in[9];
    const float* b1 = (const float*)d_in[10];
    const float* W1r = (const float*)d_in[11];
    const float* g1 = (const float*)d_in[12];
    const float* be1 = (const float*)d_in[13];
    const float* W2l = (const float*)d_in[14];
    const float* b2 = (const float*)d_in[15];
    const float* W2r = (const float*)d_in[16];
    const float* g2 = (const float*)d_in[17];
    const float* be2 = (const float*)d_in[18];
    const float* Wout = (const float*)d_in[19];
    const float* bout = (const float*)d_in[20];

    const int* src = ei;
    const int* dst = ei + NE;

    float* ws = (float*)d_ws;
    float* x0 = ws;                                // NN*40 f
    float* agg = x0 + (size_t)NN * FIN1;           // NN*64 f
    float* hbuf = agg + (size_t)NN * HID;          // NN*64 f
    float* h2 = hbuf + (size_t)NN * HID;           // NN*64 f
    float* stats = h2 + (size_t)NN * HID;          // 256 f
    int* row_ptr = (int*)(stats + 256);            // NN+1 i
    int* cursor = row_ptr + NN + 1;                // NN i
    int* bsum = cursor + NN;                       // 256 i
    int* boffs = bsum + 256;                       // 256 i
    int* gstart = boffs + 256;                     // NG+1 i
    int* eidx = gstart + NG + 1;                   // NE i

    hipMemsetAsync(cursor, 0, NN * sizeof(int), stream);
    hipMemsetAsync(stats, 0, 256 * sizeof(float), stream);

    const int B = 256;

    // features
    embed_kernel<<<(NN * FIN1 + B - 1) / B, B, 0, stream>>>(sid, cid, pid, stab, ctab, ptab, x0);

    // CSR build (shared across both layers)
    deg_hist<<<(NE + B - 1) / B, B, 0, stream>>>(dst, cursor);
    scan_a<<<SNB, SCHUNK, 0, stream>>>(cursor, bsum);
    scan_b<<<1, 256, 0, stream>>>(bsum, boffs);
    scan_c<<<SNB, SCHUNK, 0, stream>>>(cursor, boffs, row_ptr);
    csr_fill<<<(NE + B - 1) / B, B, 0, stream>>>(src, dst, cursor, eidx);

    // graph boundaries (independent; any time before pool_out)
    graph_bounds<<<(NN + B - 1) / B, B, 0, stream>>>(batch, gstart);

    // ---- layer 1 ----
    gather_agg<FIN1><<<(NN * 64 + B - 1) / B, B, 0, stream>>>(row_ptr, eidx, x0, agg);
    linear16<FIN1><<<(NN + 15) / 16, B, 0, stream>>>(x0, agg, row_ptr, W1l, W1r, b1, hbuf);
    bn_stats<<<(NN + 511) / 512, B, 0, stream>>>(hbuf, stats);
    bn_apply_relu<<<(NN * HID + B - 1) / B, B, 0, stream>>>(hbuf, stats, g1, be1, hbuf);

    // ---- layer 2 ----
    gather_agg<HID><<<(NN * 64 + B - 1) / B, B, 0, stream>>>(row_ptr, eidx, hbuf, agg);
    linear16<HID><<<(NN + 15) / 16, B, 0, stream>>>(hbuf, agg, row_ptr, W2l, W2r, b2, h2);
    bn_stats<<<(NN + 511) / 512, B, 0, stream>>>(h2, stats + 128);

    // ---- fused BN2+ReLU+pool+head ----
    pool_out<<<(NG * 64 + B - 1) / B, B, 0, stream>>>(h2, stats + 128, g2, be2, gstart,
                                                      Wout, bout, (float*)d_out);
}

// Round 6
// 453.730 us; speedup vs baseline: 1.3084x; 1.0896x over previous
//
#include <hip/hip_runtime.h>

#define NN 80000
#define NE 1280000
#define NG 2000
#define HID 64
#define FIN1 40
#define SCHUNK 512
#define SNB ((NN + SCHUNK - 1) / SCHUNK)   // 157 blocks
#define NBUK ((NN + 127) >> 7)             // 625 buckets of 128 nodes
#define BIN_PER 4096
constexpr float EPS = 1e-5f;

// ---------------- embed: x0[n][f] = concat(shape_tab, color_tab, pos_tab) ----
__global__ void embed_kernel(const int* __restrict__ sid, const int* __restrict__ cid,
                             const int* __restrict__ pid,
                             const float* __restrict__ stab, const float* __restrict__ ctab,
                             const float* __restrict__ ptab,
                             float* __restrict__ x0) {
    int idx = blockIdx.x * blockDim.x + threadIdx.x;
    if (idx >= NN * FIN1) return;
    int n = idx / FIN1;
    int f = idx - n * FIN1;
    float v;
    if (f < 16)      v = stab[sid[n] * 16 + f];
    else if (f < 32) v = ctab[cid[n] * 16 + (f - 16)];
    else             v = ptab[pid[n] * 8 + (f - 32)];
    x0[idx] = v;
}

// ---------------- degree hist (for row_ptr) ----------------
__global__ void deg_hist(const int* __restrict__ dst, int* __restrict__ cursor) {
    int e = blockIdx.x * blockDim.x + threadIdx.x;
    if (e >= NE) return;
    atomicAdd(&cursor[dst[e]], 1);
}

__global__ void scan_a(const int* __restrict__ cursor, int* __restrict__ bsum) {
    __shared__ int l[SCHUNK];
    int t = threadIdx.x;
    int idx = blockIdx.x * SCHUNK + t;
    l[t] = (idx < NN) ? cursor[idx] : 0;
    __syncthreads();
    for (int off = SCHUNK / 2; off >= 1; off >>= 1) {
        if (t < off) l[t] += l[t + off];
        __syncthreads();
    }
    if (t == 0) bsum[blockIdx.x] = l[0];
}

__global__ void scan_b(const int* __restrict__ bsum, int* __restrict__ boffs) {
    __shared__ int l[256];
    int t = threadIdx.x;
    l[t] = (t < SNB) ? bsum[t] : 0;
    __syncthreads();
    for (int off = 1; off < 256; off <<= 1) {
        int v = (t >= off) ? l[t - off] : 0;
        __syncthreads();
        l[t] += v;
        __syncthreads();
    }
    boffs[t] = (t == 0) ? 0 : l[t - 1];
}

__global__ void scan_c(const int* __restrict__ cursor, const int* __restrict__ boffs,
                       int* __restrict__ row_ptr) {
    __shared__ int l[SCHUNK];
    int t = threadIdx.x;
    int idx = blockIdx.x * SCHUNK + t;
    l[t] = (idx < NN) ? cursor[idx] : 0;
    __syncthreads();
    for (int off = 1; off < SCHUNK; off <<= 1) {
        int v = (t >= off) ? l[t - off] : 0;
        __syncthreads();
        l[t] += v;
        __syncthreads();
    }
    int excl = ((t == 0) ? 0 : l[t - 1]) + boffs[blockIdx.x];
    if (idx < NN) row_ptr[idx] = excl;
    if (idx == 0) row_ptr[NN] = NE;
}

// ---------------- bucket binning (locality for eidx fill) ----------------
__global__ void bucket_hist(const int* __restrict__ dst, int* __restrict__ bcnt) {
    __shared__ int lh[NBUK];
    for (int i = threadIdx.x; i < NBUK; i += 256) lh[i] = 0;
    __syncthreads();
    int e0 = blockIdx.x * BIN_PER;
    int e1 = min(e0 + BIN_PER, NE);
    for (int e = e0 + threadIdx.x; e < e1; e += 256) atomicAdd(&lh[dst[e] >> 7], 1);
    __syncthreads();
    for (int i = threadIdx.x; i < NBUK; i += 256)
        if (lh[i]) atomicAdd(&bcnt[i], lh[i]);
}

__global__ void bucket_scan(const int* __restrict__ bcnt, int* __restrict__ bstart,
                            int* __restrict__ bcur) {
    __shared__ int l[1024];
    int t = threadIdx.x;
    l[t] = (t < NBUK) ? bcnt[t] : 0;
    __syncthreads();
    for (int off = 1; off < 1024; off <<= 1) {
        int v = (t >= off) ? l[t - off] : 0;
        __syncthreads();
        l[t] += v;
        __syncthreads();
    }
    int excl = (t == 0) ? 0 : l[t - 1];
    if (t < NBUK) { bstart[t] = excl; bcur[t] = excl; }
    if (t == NBUK) bstart[NBUK] = NE;
}

// two-phase per block: LDS hist -> one range-reservation atomic per bucket ->
// place edges via LDS cursors. Writes per bucket are sequential runs.
__global__ void bin_edges(const int* __restrict__ src, const int* __restrict__ dst,
                          int* __restrict__ bcur, int2* __restrict__ ebuf) {
    __shared__ int lh[NBUK];
    __shared__ int lbase[NBUK];
    for (int i = threadIdx.x; i < NBUK; i += 256) lh[i] = 0;
    __syncthreads();
    int e0 = blockIdx.x * BIN_PER;
    int e1 = min(e0 + BIN_PER, NE);
    for (int e = e0 + threadIdx.x; e < e1; e += 256) atomicAdd(&lh[dst[e] >> 7], 1);
    __syncthreads();
    for (int i = threadIdx.x; i < NBUK; i += 256) {
        int c = lh[i];
        lbase[i] = c ? atomicAdd(&bcur[i], c) : 0;
    }
    __syncthreads();
    for (int i = threadIdx.x; i < NBUK; i += 256) lh[i] = 0;
    __syncthreads();
    for (int e = e0 + threadIdx.x; e < e1; e += 256) {
        int d = dst[e];
        int b = d >> 7;
        int off = atomicAdd(&lh[b], 1);
        ebuf[lbase[b] + off] = make_int2(src[e], d);
    }
}

// one block per bucket; LDS-local cursors; eidx writes confined to ~8KB window
__global__ void csr_fill2(const int2* __restrict__ ebuf, const int* __restrict__ bstart,
                          const int* __restrict__ row_ptr, int* __restrict__ eidx) {
    __shared__ int lcur[128];
    int b = blockIdx.x;
    int t = threadIdx.x;
    int nbase = b << 7;
    if (t < 128) {
        int n = nbase + t;
        lcur[t] = (n < NN) ? row_ptr[n] : 0;
    }
    __syncthreads();
    int s0 = bstart[b], s1 = bstart[b + 1];
    for (int i = s0 + t; i < s1; i += 256) {
        int2 ed = ebuf[i];
        int pos = atomicAdd(&lcur[ed.y - nbase], 1);
        eidx[pos] = ed.x;
    }
}

// ---------------- gather-aggregate (optionally fused BN1+ReLU on loads) ----
template <int F, bool BN>
__global__ void gather_agg(const int* __restrict__ row_ptr, const int* __restrict__ eidx,
                           const float* __restrict__ x, float* __restrict__ agg,
                           const float* __restrict__ stats, const float* __restrict__ g,
                           const float* __restrict__ be) {
    int t = blockIdx.x * blockDim.x + threadIdx.x;
    int n = t >> 6;
    int lane = threadIdx.x & 63;
    if (n >= NN) return;
    int grp = lane >> 4;        // group 0..3
    int fl = (lane & 15) * 4;   // feature base for this lane
    float4 sc4, sh4;
    if (BN) {
        const float invn = 1.0f / (float)NN;
        float4 s = *(const float4*)&stats[fl];
        float4 sq = *(const float4*)&stats[64 + fl];
        float4 gg = *(const float4*)&g[fl];
        float4 bb = *(const float4*)&be[fl];
        float m;
        m = s.x * invn; sc4.x = gg.x * __frsqrt_rn(sq.x * invn - m * m + EPS); sh4.x = bb.x - m * sc4.x;
        m = s.y * invn; sc4.y = gg.y * __frsqrt_rn(sq.y * invn - m * m + EPS); sh4.y = bb.y - m * sc4.y;
        m = s.z * invn; sc4.z = gg.z * __frsqrt_rn(sq.z * invn - m * m + EPS); sh4.z = bb.z - m * sc4.z;
        m = s.w * invn; sc4.w = gg.w * __frsqrt_rn(sq.w * invn - m * m + EPS); sh4.w = bb.w - m * sc4.w;
    }
    int beg = row_ptr[n];
    int end = row_ptr[n + 1];
    float4 acc = make_float4(0.f, 0.f, 0.f, 0.f);
    for (int j0 = beg; j0 < end; j0 += 64) {
        int cnt = min(64, end - j0);
        int myid = (j0 + lane < end) ? eidx[j0 + lane] : 0;
        int steps = (cnt + 3) >> 2;
        for (int u = 0; u < steps; u++) {
            int e = u * 4 + grp;
            int s = __shfl(myid, e);
            if (e < cnt && fl < F) {
                float4 v = *(const float4*)&x[(size_t)s * F + fl];
                if (BN) {
                    v.x = fmaxf(fmaf(v.x, sc4.x, sh4.x), 0.f);
                    v.y = fmaxf(fmaf(v.y, sc4.y, sh4.y), 0.f);
                    v.z = fmaxf(fmaf(v.z, sc4.z, sh4.z), 0.f);
                    v.w = fmaxf(fmaf(v.w, sc4.w, sh4.w), 0.f);
                }
                acc.x += v.x; acc.y += v.y; acc.z += v.z; acc.w += v.w;
            }
        }
    }
#pragma unroll
    for (int m = 16; m <= 32; m <<= 1) {
        acc.x += __shfl_xor(acc.x, m);
        acc.y += __shfl_xor(acc.y, m);
        acc.z += __shfl_xor(acc.z, m);
        acc.w += __shfl_xor(acc.w, m);
    }
    if (lane < 16 && fl < F) {
        *(float4*)&agg[(size_t)n * F + fl] = acc;
    }
}

// ---------------- linear: h = (agg/deg) @ Wl + b + xr @ Wr ----------------
// block = 16 nodes; thread = (node, j-quad); float4 acc; optional BN1 on xr.
template <int FIN, bool BN>
__launch_bounds__(256)
__global__ void linear16(const float* __restrict__ x, const float* __restrict__ agg,
                         const int* __restrict__ row_ptr,
                         const float* __restrict__ Wl, const float* __restrict__ Wr,
                         const float* __restrict__ b, float* __restrict__ h,
                         const float* __restrict__ stats, const float* __restrict__ g,
                         const float* __restrict__ be) {
    __shared__ float sxa[16 * FIN];
    __shared__ float sxr[16 * FIN];
    __shared__ float sinv[16];
    __shared__ float ssc[FIN];
    __shared__ float ssh[FIN];

    int tid = threadIdx.x;
    int n0 = blockIdx.x * 16;

    if (tid < 16) {
        int n = n0 + tid;
        int deg = (n < NN) ? (row_ptr[n + 1] - row_ptr[n]) : 1;
        sinv[tid] = 1.0f / (float)max(deg, 1);
    }
    if (BN && tid < FIN) {
        const float invn = 1.0f / (float)NN;
        float m = stats[tid] * invn;
        float var = stats[64 + tid] * invn - m * m;
        float sc = g[tid] * __frsqrt_rn(var + EPS);
        ssc[tid] = sc;
        ssh[tid] = be[tid] - m * sc;
    }
    __syncthreads();
    int limit = min(16, NN - n0) * FIN;
    for (int i = tid; i < limit; i += 256) {
        int r = i / FIN;
        int f = i - r * FIN;
        sxa[i] = agg[(size_t)n0 * FIN + i] * sinv[r];
        float xr = x[(size_t)n0 * FIN + i];
        if (BN) xr = fmaxf(fmaf(xr, ssc[f], ssh[f]), 0.f);
        sxr[i] = xr;
    }
    __syncthreads();

    int r = tid >> 4;
    int j = (tid & 15) * 4;
    int n = n0 + r;
    if (n >= NN) return;

    float4 acc = *(const float4*)&b[j];
#pragma unroll 8
    for (int k = 0; k < FIN; k++) {
        float xa = sxa[r * FIN + k];
        float xr = sxr[r * FIN + k];
        const float4 wl = *(const float4*)&Wl[k * HID + j];
        const float4 wr = *(const float4*)&Wr[k * HID + j];
        acc.x = fmaf(xa, wl.x, fmaf(xr, wr.x, acc.x));
        acc.y = fmaf(xa, wl.y, fmaf(xr, wr.y, acc.y));
        acc.z = fmaf(xa, wl.z, fmaf(xr, wr.z, acc.z));
        acc.w = fmaf(xa, wl.w, fmaf(xr, wr.w, acc.w));
    }
    *(float4*)&h[(size_t)n * HID + j] = acc;
}

// ---------------- BN stats: stats[f] = sum, stats[64+f] = sumsq -------------
__global__ void bn_stats(const float* __restrict__ h, float* __restrict__ stats) {
    const int NPB = 512;
    int f = threadIdx.x & 63;
    int r = threadIdx.x >> 6;
    int n0 = blockIdx.x * NPB;
    int nend = min(n0 + NPB, NN);
    float s = 0.f, ss = 0.f;
    for (int n = n0 + r; n < nend; n += 4) {
        float v = h[n * HID + f];
        s += v;
        ss += v * v;
    }
    __shared__ float ls[4][64];
    __shared__ float lss[4][64];
    ls[r][f] = s;
    lss[r][f] = ss;
    __syncthreads();
    if (r == 0) {
        s = ls[0][f] + ls[1][f] + ls[2][f] + ls[3][f];
        ss = lss[0][f] + lss[1][f] + lss[2][f] + lss[3][f];
        atomicAdd(&stats[f], s);
        atomicAdd(&stats[64 + f], ss);
    }
}

// ---------------- graph boundaries from sorted batch ----------------
__global__ void graph_bounds(const int* __restrict__ batch, int* __restrict__ gstart) {
    int n = blockIdx.x * blockDim.x + threadIdx.x;
    if (n >= NN) return;
    int cur = batch[n];
    int prev = (n == 0) ? -1 : batch[n - 1];
    for (int g = prev + 1; g <= cur; g++) gstart[g] = n;
    if (n == NN - 1) {
        for (int g = cur + 1; g <= NG; g++) gstart[g] = NN;
    }
}

// ---------------- fused layer2-BN+ReLU + mean-pool + output GEMV ------------
__global__ void pool_out(const float* __restrict__ h, const float* __restrict__ stats2,
                         const float* __restrict__ g2, const float* __restrict__ be2,
                         const int* __restrict__ gstart,
                         const float* __restrict__ Wout, const float* __restrict__ bout,
                         float* __restrict__ out) {
    int w = (blockIdx.x * blockDim.x + threadIdx.x) >> 6;
    int f = threadIdx.x & 63;
    if (w >= NG) return;
    const float invn = 1.0f / (float)NN;
    float m = stats2[f] * invn;
    float var = stats2[64 + f] * invn - m * m;
    float sc = g2[f] / sqrtf(var + EPS);
    float bb = be2[f];
    int n0 = gstart[w], n1 = gstart[w + 1];
    float acc = 0.f;
    for (int n = n0; n < n1; n++) {
        float v = (h[(size_t)n * HID + f] - m) * sc + bb;
        acc += fmaxf(v, 0.0f);
    }
    float inv = 1.0f / (float)max(n1 - n0, 1);
    float p = acc * inv;
    float a0 = p * Wout[f * 2 + 0];
    float a1 = p * Wout[f * 2 + 1];
#pragma unroll
    for (int mm = 1; mm < 64; mm <<= 1) {
        a0 += __shfl_xor(a0, mm);
        a1 += __shfl_xor(a1, mm);
    }
    if (f == 0) {
        out[w * 2 + 0] = a0 + bout[0];
        out[w * 2 + 1] = a1 + bout[1];
    }
}

extern "C" void kernel_launch(void* const* d_in, const int* in_sizes, int n_in,
                              void* d_out, int out_size, void* d_ws, size_t ws_size,
                              hipStream_t stream) {
    const int* sid = (const int*)d_in[0];
    const int* cid = (const int*)d_in[1];
    const int* pid = (const int*)d_in[2];
    const int* ei = (const int*)d_in[3];
    const int* batch = (const int*)d_in[4];
    const float* stab = (const float*)d_in[6];
    const float* ctab = (const float*)d_in[7];
    const float* ptab = (const float*)d_in[8];
    const float* W1l = (const float*)d_in[9];
    const float* b1 = (const float*)d_in[10];
    const float* W1r = (const float*)d_in[11];
    const float* g1 = (const float*)d_in[12];
    const float* be1 = (const float*)d_in[13];
    const float* W2l = (const float*)d_in[14];
    const float* b2 = (const float*)d_in[15];
    const float* W2r = (const float*)d_in[16];
    const float* g2 = (const float*)d_in[17];
    const float* be2 = (const float*)d_in[18];
    const float* Wout = (const float*)d_in[19];
    const float* bout = (const float*)d_in[20];

    const int* src = ei;
    const int* dst = ei + NE;

    float* ws = (float*)d_ws;
    float* x0 = ws;                                // NN*40 f
    float* agg = x0 + (size_t)NN * FIN1;           // NN*64 f (also aliased as ebuf pre-gather)
    float* hbuf = agg + (size_t)NN * HID;          // NN*64 f
    float* h2 = hbuf + (size_t)NN * HID;           // NN*64 f
    float* stats = h2 + (size_t)NN * HID;          // 256 f
    int* row_ptr = (int*)(stats + 256);            // NN+1 i
    int* cursor = row_ptr + NN + 1;                // NN i
    int* bsum = cursor + NN;                       // 256 i
    int* boffs = bsum + 256;                       // 256 i
    int* gstart = boffs + 256;                     // NG+1 i
    int* bcnt = gstart + NG + 1;                   // NBUK i
    int* bstart = bcnt + NBUK;                     // NBUK+1 i
    int* bcur = bstart + NBUK + 1;                 // NBUK i
    int* eidx = bcur + NBUK;                       // NE i
    int2* ebuf = (int2*)agg;                       // NE int2, dead before gather_agg

    hipMemsetAsync(cursor, 0, NN * sizeof(int), stream);
    hipMemsetAsync(bcnt, 0, NBUK * sizeof(int), stream);
    hipMemsetAsync(stats, 0, 256 * sizeof(float), stream);

    const int B = 256;

    // features
    embed_kernel<<<(NN * FIN1 + B - 1) / B, B, 0, stream>>>(sid, cid, pid, stab, ctab, ptab, x0);

    // degrees -> row_ptr
    deg_hist<<<(NE + B - 1) / B, B, 0, stream>>>(dst, cursor);
    scan_a<<<SNB, SCHUNK, 0, stream>>>(cursor, bsum);
    scan_b<<<1, 256, 0, stream>>>(bsum, boffs);
    scan_c<<<SNB, SCHUNK, 0, stream>>>(cursor, boffs, row_ptr);

    // bucket-binned edge fill
    bucket_hist<<<(NE + BIN_PER - 1) / BIN_PER, B, 0, stream>>>(dst, bcnt);
    bucket_scan<<<1, 1024, 0, stream>>>(bcnt, bstart, bcur);
    bin_edges<<<(NE + BIN_PER - 1) / BIN_PER, B, 0, stream>>>(src, dst, bcur, ebuf);
    csr_fill2<<<NBUK, B, 0, stream>>>(ebuf, bstart, row_ptr, eidx);

    // graph boundaries (independent; any time before pool_out)
    graph_bounds<<<(NN + B - 1) / B, B, 0, stream>>>(batch, gstart);

    // ---- layer 1 ----
    gather_agg<FIN1, false><<<(NN * 64 + B - 1) / B, B, 0, stream>>>(
        row_ptr, eidx, x0, agg, nullptr, nullptr, nullptr);
    linear16<FIN1, false><<<(NN + 15) / 16, B, 0, stream>>>(
        x0, agg, row_ptr, W1l, W1r, b1, hbuf, nullptr, nullptr, nullptr);
    bn_stats<<<(NN + 511) / 512, B, 0, stream>>>(hbuf, stats);

    // ---- layer 2 (BN1+ReLU fused into gather & linear xr staging) ----
    gather_agg<HID, true><<<(NN * 64 + B - 1) / B, B, 0, stream>>>(
        row_ptr, eidx, hbuf, agg, stats, g1, be1);
    linear16<HID, true><<<(NN + 15) / 16, B, 0, stream>>>(
        hbuf, agg, row_ptr, W2l, W2r, b2, h2, stats, g1, be1);
    bn_stats<<<(NN + 511) / 512, B, 0, stream>>>(h2, stats + 128);

    // ---- fused BN2+ReLU+pool+head ----
    pool_out<<<(NG * 64 + B - 1) / B, B, 0, stream>>>(h2, stats + 128, g2, be2, gstart,
                                                      Wout, bout, (float*)d_out);
}

// Round 7
// 286.648 us; speedup vs baseline: 2.0711x; 1.5829x over previous
//
#include <hip/hip_runtime.h>

#define NN 80000
#define NE 1280000
#define NG 2000
#define HID 64
#define FIN1 40
#define NBUK ((NN + 127) >> 7)             // 625 buckets of 128 nodes (NN = 625*128 exactly)
#define BIN_PER 4096
constexpr float EPS = 1e-5f;

typedef _Float16 f16;
typedef f16 f16x4 __attribute__((ext_vector_type(4)));
typedef f16 f16x8 __attribute__((ext_vector_type(8)));
typedef float f32x4 __attribute__((ext_vector_type(4)));

// ---------------- embed: x0[n][f] = concat(shape_tab, color_tab, pos_tab) ----
__global__ void embed_kernel(const int* __restrict__ sid, const int* __restrict__ cid,
                             const int* __restrict__ pid,
                             const float* __restrict__ stab, const float* __restrict__ ctab,
                             const float* __restrict__ ptab,
                             float* __restrict__ x0) {
    int idx = blockIdx.x * blockDim.x + threadIdx.x;
    if (idx >= NN * FIN1) return;
    int n = idx / FIN1;
    int f = idx - n * FIN1;
    float v;
    if (f < 16)      v = stab[sid[n] * 16 + f];
    else if (f < 32) v = ctab[cid[n] * 16 + (f - 16)];
    else             v = ptab[pid[n] * 8 + (f - 32)];
    x0[idx] = v;
}

// ---------------- W prep: Bt[j][k] = [Wl;Wr]^T as f16, padded ----------------
// Bt1: 64 x 104 (k<40: W1l, k<80: W1r, else 0). Bt2: 64 x 136 (k<64: W2l, k<128: W2r).
__global__ void wprep(const float* __restrict__ W1l, const float* __restrict__ W1r,
                      const float* __restrict__ W2l, const float* __restrict__ W2r,
                      f16* __restrict__ Bt1, f16* __restrict__ Bt2) {
    int i = blockIdx.x * 256 + threadIdx.x;
    if (i < 64 * 104) {
        int j = i / 104, k = i - j * 104;
        float v = 0.f;
        if (k < 40) v = W1l[k * 64 + j];
        else if (k < 80) v = W1r[(k - 40) * 64 + j];
        Bt1[i] = (f16)v;
    }
    int i2 = i - 64 * 104;
    if (i2 >= 0 && i2 < 64 * 136) {
        int j = i2 / 136, k = i2 - j * 136;
        float v = 0.f;
        if (k < 64) v = W2l[k * 64 + j];
        else if (k < 128) v = W2r[(k - 64) * 64 + j];
        Bt2[i2] = (f16)v;
    }
}

// ---------------- bucket binning ----------------
__global__ void bucket_hist(const int* __restrict__ dst, int* __restrict__ bcnt) {
    __shared__ int lh[NBUK];
    for (int i = threadIdx.x; i < NBUK; i += 256) lh[i] = 0;
    __syncthreads();
    int e0 = blockIdx.x * BIN_PER;
    int e1 = min(e0 + BIN_PER, NE);
    for (int e = e0 + threadIdx.x; e < e1; e += 256) atomicAdd(&lh[dst[e] >> 7], 1);
    __syncthreads();
    for (int i = threadIdx.x; i < NBUK; i += 256)
        if (lh[i]) atomicAdd(&bcnt[i], lh[i]);
}

__global__ void bucket_scan(const int* __restrict__ bcnt, int* __restrict__ bstart,
                            int* __restrict__ bcur) {
    __shared__ int l[1024];
    int t = threadIdx.x;
    l[t] = (t < NBUK) ? bcnt[t] : 0;
    __syncthreads();
    for (int off = 1; off < 1024; off <<= 1) {
        int v = (t >= off) ? l[t - off] : 0;
        __syncthreads();
        l[t] += v;
        __syncthreads();
    }
    int excl = (t == 0) ? 0 : l[t - 1];
    if (t < NBUK) { bstart[t] = excl; bcur[t] = excl; }
    if (t == NBUK) bstart[NBUK] = NE;
}

// pack src (17b) + local dst (7b) into one int; bucketed sequential write runs
__global__ void bin_edges(const int* __restrict__ src, const int* __restrict__ dst,
                          int* __restrict__ bcur, int* __restrict__ ebuf) {
    __shared__ int lh[NBUK];
    __shared__ int lbase[NBUK];
    for (int i = threadIdx.x; i < NBUK; i += 256) lh[i] = 0;
    __syncthreads();
    int e0 = blockIdx.x * BIN_PER;
    int e1 = min(e0 + BIN_PER, NE);
    for (int e = e0 + threadIdx.x; e < e1; e += 256) atomicAdd(&lh[dst[e] >> 7], 1);
    __syncthreads();
    for (int i = threadIdx.x; i < NBUK; i += 256) {
        int c = lh[i];
        lbase[i] = c ? atomicAdd(&bcur[i], c) : 0;
    }
    __syncthreads();
    for (int i = threadIdx.x; i < NBUK; i += 256) lh[i] = 0;
    __syncthreads();
    for (int e = e0 + threadIdx.x; e < e1; e += 256) {
        int d = dst[e];
        int b = d >> 7;
        int off = atomicAdd(&lh[b], 1);
        ebuf[lbase[b] + off] = (src[e] << 7) | (d & 127);
    }
}

// one block per bucket: local hist -> local scan -> row_ptr AND eidx fill.
// (deg_hist + global scan eliminated: row_ptr[n] = bstart[b] + local prefix)
__global__ void csr_fill2(const int* __restrict__ ebuf, const int* __restrict__ bstart,
                          int* __restrict__ row_ptr, int* __restrict__ eidx) {
    __shared__ int cnt[128];
    __shared__ int sb[128];
    __shared__ int lcur[128];
    int b = blockIdx.x;
    int t = threadIdx.x;
    int nbase = b << 7;
    if (t < 128) cnt[t] = 0;
    __syncthreads();
    int s0 = bstart[b], s1 = bstart[b + 1];
    for (int i = s0 + t; i < s1; i += 256) atomicAdd(&cnt[ebuf[i] & 127], 1);
    __syncthreads();
    if (t < 128) sb[t] = cnt[t];
    __syncthreads();
    for (int off = 1; off < 128; off <<= 1) {
        int v = (t >= off && t < 128) ? sb[t - off] : 0;
        __syncthreads();
        if (t < 128) sb[t] += v;
        __syncthreads();
    }
    if (t < 128) {
        int excl = ((t == 0) ? 0 : sb[t - 1]) + s0;
        row_ptr[nbase + t] = excl;
        lcur[t] = excl;
    }
    if (b == 0 && t == 0) row_ptr[NN] = NE;
    __syncthreads();
    for (int i = s0 + t; i < s1; i += 256) {
        int v = ebuf[i];
        int pos = atomicAdd(&lcur[v & 127], 1);
        eidx[pos] = v >> 7;
    }
}

// ---------------- gather-aggregate (optionally fused BN1+ReLU on loads) ----
template <int F, bool BN>
__global__ void gather_agg(const int* __restrict__ row_ptr, const int* __restrict__ eidx,
                           const float* __restrict__ x, float* __restrict__ agg,
                           const float* __restrict__ stats, const float* __restrict__ g,
                           const float* __restrict__ be) {
    int t = blockIdx.x * blockDim.x + threadIdx.x;
    int n = t >> 6;
    int lane = threadIdx.x & 63;
    if (n >= NN) return;
    int grp = lane >> 4;
    int fl = (lane & 15) * 4;
    float4 sc4, sh4;
    if (BN) {
        const float invn = 1.0f / (float)NN;
        float4 s = *(const float4*)&stats[fl];
        float4 sq = *(const float4*)&stats[64 + fl];
        float4 gg = *(const float4*)&g[fl];
        float4 bb = *(const float4*)&be[fl];
        float m;
        m = s.x * invn; sc4.x = gg.x * __frsqrt_rn(sq.x * invn - m * m + EPS); sh4.x = bb.x - m * sc4.x;
        m = s.y * invn; sc4.y = gg.y * __frsqrt_rn(sq.y * invn - m * m + EPS); sh4.y = bb.y - m * sc4.y;
        m = s.z * invn; sc4.z = gg.z * __frsqrt_rn(sq.z * invn - m * m + EPS); sh4.z = bb.z - m * sc4.z;
        m = s.w * invn; sc4.w = gg.w * __frsqrt_rn(sq.w * invn - m * m + EPS); sh4.w = bb.w - m * sc4.w;
    }
    int beg = row_ptr[n];
    int end = row_ptr[n + 1];
    float4 acc = make_float4(0.f, 0.f, 0.f, 0.f);
    for (int j0 = beg; j0 < end; j0 += 64) {
        int cnt = min(64, end - j0);
        int myid = (j0 + lane < end) ? eidx[j0 + lane] : 0;
        int steps = (cnt + 3) >> 2;
        for (int u = 0; u < steps; u++) {
            int e = u * 4 + grp;
            int s = __shfl(myid, e);
            if (e < cnt && fl < F) {
                float4 v = *(const float4*)&x[(size_t)s * F + fl];
                if (BN) {
                    v.x = fmaxf(fmaf(v.x, sc4.x, sh4.x), 0.f);
                    v.y = fmaxf(fmaf(v.y, sc4.y, sh4.y), 0.f);
                    v.z = fmaxf(fmaf(v.z, sc4.z, sh4.z), 0.f);
                    v.w = fmaxf(fmaf(v.w, sc4.w, sh4.w), 0.f);
                }
                acc.x += v.x; acc.y += v.y; acc.z += v.z; acc.w += v.w;
            }
        }
    }
#pragma unroll
    for (int m = 16; m <= 32; m <<= 1) {
        acc.x += __shfl_xor(acc.x, m);
        acc.y += __shfl_xor(acc.y, m);
        acc.z += __shfl_xor(acc.z, m);
        acc.w += __shfl_xor(acc.w, m);
    }
    if (lane < 16 && fl < F) {
        *(float4*)&agg[(size_t)n * F + fl] = acc;
    }
}

// ---------------- MFMA SAGE linear: h = [xa|xr] @ [Wl;Wr] + b ----------------
// block = 64 nodes, 4 waves; wave w -> nodes [w*16, w*16+16), all 64 j.
// A (f16, LDS): row = node, k = [xa(FIN) | xr(FIN) | pad]; B staged from prepped Bt.
template <int FIN, int KTOT, int KP, bool BN>
__launch_bounds__(256)
__global__ void sage_mfma(const float* __restrict__ x, const float* __restrict__ agg,
                          const int* __restrict__ row_ptr, const f16* __restrict__ Btg,
                          const float* __restrict__ bias, float* __restrict__ h,
                          const float* __restrict__ stats, const float* __restrict__ g,
                          const float* __restrict__ be) {
    __shared__ f16 Asm[64 * KP];
    __shared__ f16 Bsm[64 * KP];
    __shared__ float sinv[64];
    __shared__ float ssc[HID];
    __shared__ float ssh[HID];

    int tid = threadIdx.x;
    int n0 = blockIdx.x * 64;

    if (tid < 64) {
        int n = n0 + tid;
        int deg = row_ptr[n + 1] - row_ptr[n];
        sinv[tid] = 1.0f / (float)max(deg, 1);
        if (BN) {
            const float invn = 1.0f / (float)NN;
            float m = stats[tid] * invn;
            float var = stats[64 + tid] * invn - m * m;
            float sc = g[tid] * __frsqrt_rn(var + EPS);
            ssc[tid] = sc;
            ssh[tid] = be[tid] - m * sc;
        }
    }
    __syncthreads();

    // stage A: xa = agg/deg, xr = x (BN+relu if layer2)
    const int C4 = FIN / 4;
    for (int i = tid; i < 64 * C4; i += 256) {
        int r = i / C4, c = i - r * C4;
        float inv = sinv[r];
        float4 va = *(const float4*)&agg[(size_t)(n0 + r) * FIN + c * 4];
        float4 vx = *(const float4*)&x[(size_t)(n0 + r) * FIN + c * 4];
        if (BN) {
            int f = c * 4;
            vx.x = fmaxf(fmaf(vx.x, ssc[f + 0], ssh[f + 0]), 0.f);
            vx.y = fmaxf(fmaf(vx.y, ssc[f + 1], ssh[f + 1]), 0.f);
            vx.z = fmaxf(fmaf(vx.z, ssc[f + 2], ssh[f + 2]), 0.f);
            vx.w = fmaxf(fmaf(vx.w, ssc[f + 3], ssh[f + 3]), 0.f);
        }
        f16x4 pa, pxr;
        pa[0] = (f16)(va.x * inv); pa[1] = (f16)(va.y * inv);
        pa[2] = (f16)(va.z * inv); pa[3] = (f16)(va.w * inv);
        pxr[0] = (f16)vx.x; pxr[1] = (f16)vx.y; pxr[2] = (f16)vx.z; pxr[3] = (f16)vx.w;
        *(f16x4*)&Asm[r * KP + c * 4] = pa;
        *(f16x4*)&Asm[r * KP + FIN + c * 4] = pxr;
    }
    if constexpr (KTOT != 2 * FIN) {   // zero-pad k in [2*FIN, KTOT)
        const int PADW = KTOT - 2 * FIN;
        for (int i = tid; i < 64 * PADW; i += 256) {
            int r = i / PADW, k = 2 * FIN + (i - r * PADW);
            Asm[r * KP + k] = (f16)0.f;
        }
    }
    // stage B (flat copy of prepped image)
    const int NU4 = 64 * KP * 2 / 16;
    for (int i = tid; i < NU4; i += 256)
        ((uint4*)Bsm)[i] = ((const uint4*)Btg)[i];
    __syncthreads();

    int w = tid >> 6;
    int l = tid & 63;
    int jloc = l & 15;
    int kg = l >> 4;
    int rbase = w * 16;

    f32x4 acc[4];
#pragma unroll
    for (int jt = 0; jt < 4; jt++) {
        float bj = bias[jt * 16 + jloc];
        acc[jt] = (f32x4){bj, bj, bj, bj};
    }
#pragma unroll
    for (int kk = 0; kk < KTOT / 32; kk++) {
        f16x8 af = *(const f16x8*)&Asm[(rbase + jloc) * KP + kk * 32 + kg * 8];
#pragma unroll
        for (int jt = 0; jt < 4; jt++) {
            f16x8 bf = *(const f16x8*)&Bsm[(jt * 16 + jloc) * KP + kk * 32 + kg * 8];
            acc[jt] = __builtin_amdgcn_mfma_f32_16x16x32_f16(af, bf, acc[jt], 0, 0, 0);
        }
    }
    // D: row = kg*4 + reg (node within wave tile), col = jloc
#pragma unroll
    for (int jt = 0; jt < 4; jt++) {
#pragma unroll
        for (int reg = 0; reg < 4; reg++) {
            int n = n0 + rbase + kg * 4 + reg;
            h[(size_t)n * HID + jt * 16 + jloc] = acc[jt][reg];
        }
    }
}

// ---------------- BN stats: stats[f] = sum, stats[64+f] = sumsq -------------
__global__ void bn_stats(const float* __restrict__ h, float* __restrict__ stats) {
    const int NPB = 512;
    int f = threadIdx.x & 63;
    int r = threadIdx.x >> 6;
    int n0 = blockIdx.x * NPB;
    int nend = min(n0 + NPB, NN);
    float s = 0.f, ss = 0.f;
    for (int n = n0 + r; n < nend; n += 4) {
        float v = h[n * HID + f];
        s += v;
        ss += v * v;
    }
    __shared__ float ls[4][64];
    __shared__ float lss[4][64];
    ls[r][f] = s;
    lss[r][f] = ss;
    __syncthreads();
    if (r == 0) {
        s = ls[0][f] + ls[1][f] + ls[2][f] + ls[3][f];
        ss = lss[0][f] + lss[1][f] + lss[2][f] + lss[3][f];
        atomicAdd(&stats[f], s);
        atomicAdd(&stats[64 + f], ss);
    }
}

// ---------------- graph boundaries from sorted batch ----------------
__global__ void graph_bounds(const int* __restrict__ batch, int* __restrict__ gstart) {
    int n = blockIdx.x * blockDim.x + threadIdx.x;
    if (n >= NN) return;
    int cur = batch[n];
    int prev = (n == 0) ? -1 : batch[n - 1];
    for (int g = prev + 1; g <= cur; g++) gstart[g] = n;
    if (n == NN - 1) {
        for (int g = cur + 1; g <= NG; g++) gstart[g] = NN;
    }
}

// ---------------- fused layer2-BN+ReLU + mean-pool + output GEMV ------------
__global__ void pool_out(const float* __restrict__ h, const float* __restrict__ stats2,
                         const float* __restrict__ g2, const float* __restrict__ be2,
                         const int* __restrict__ gstart,
                         const float* __restrict__ Wout, const float* __restrict__ bout,
                         float* __restrict__ out) {
    int w = (blockIdx.x * blockDim.x + threadIdx.x) >> 6;
    int f = threadIdx.x & 63;
    if (w >= NG) return;
    const float invn = 1.0f / (float)NN;
    float m = stats2[f] * invn;
    float var = stats2[64 + f] * invn - m * m;
    float sc = g2[f] / sqrtf(var + EPS);
    float bb = be2[f];
    int n0 = gstart[w], n1 = gstart[w + 1];
    float acc = 0.f;
    for (int n = n0; n < n1; n++) {
        float v = (h[(size_t)n * HID + f] - m) * sc + bb;
        acc += fmaxf(v, 0.0f);
    }
    float inv = 1.0f / (float)max(n1 - n0, 1);
    float p = acc * inv;
    float a0 = p * Wout[f * 2 + 0];
    float a1 = p * Wout[f * 2 + 1];
#pragma unroll
    for (int mm = 1; mm < 64; mm <<= 1) {
        a0 += __shfl_xor(a0, mm);
        a1 += __shfl_xor(a1, mm);
    }
    if (f == 0) {
        out[w * 2 + 0] = a0 + bout[0];
        out[w * 2 + 1] = a1 + bout[1];
    }
}

extern "C" void kernel_launch(void* const* d_in, const int* in_sizes, int n_in,
                              void* d_out, int out_size, void* d_ws, size_t ws_size,
                              hipStream_t stream) {
    const int* sid = (const int*)d_in[0];
    const int* cid = (const int*)d_in[1];
    const int* pid = (const int*)d_in[2];
    const int* ei = (const int*)d_in[3];
    const int* batch = (const int*)d_in[4];
    const float* stab = (const float*)d_in[6];
    const float* ctab = (const float*)d_in[7];
    const float* ptab = (const float*)d_in[8];
    const float* W1l = (const float*)d_in[9];
    const float* b1 = (const float*)d_in[10];
    const float* W1r = (const float*)d_in[11];
    const float* g1 = (const float*)d_in[12];
    const float* be1 = (const float*)d_in[13];
    const float* W2l = (const float*)d_in[14];
    const float* b2 = (const float*)d_in[15];
    const float* W2r = (const float*)d_in[16];
    const float* g2 = (const float*)d_in[17];
    const float* be2 = (const float*)d_in[18];
    const float* Wout = (const float*)d_in[19];
    const float* bout = (const float*)d_in[20];

    const int* src = ei;
    const int* dst = ei + NE;

    float* ws = (float*)d_ws;
    float* x0 = ws;                                // NN*40 f
    float* agg = x0 + (size_t)NN * FIN1;           // NN*64 f (aliased as ebuf pre-gather)
    float* hbuf = agg + (size_t)NN * HID;          // NN*64 f
    float* h2 = hbuf + (size_t)NN * HID;           // NN*64 f
    float* stats = h2 + (size_t)NN * HID;          // 256 f
    f16* bt1 = (f16*)(stats + 256);                // 64*104 f16 = 3328 f-slots
    f16* bt2 = bt1 + 64 * 104;                     // 64*136 f16 = 4352 f-slots
    int* row_ptr = (int*)(bt2 + 64 * 136);         // NN+1 i
    int* gstart = row_ptr + NN + 1;                // NG+1 i
    int* bcnt = gstart + NG + 1;                   // NBUK i
    int* bstart = bcnt + NBUK;                     // NBUK+1 i
    int* bcur = bstart + NBUK + 1;                 // NBUK i
    int* eidx = bcur + NBUK;                       // NE i
    int* ebuf = (int*)agg;                         // NE i, dead before gather_agg

    hipMemsetAsync(bcnt, 0, NBUK * sizeof(int), stream);
    hipMemsetAsync(stats, 0, 256 * sizeof(float), stream);

    const int B = 256;

    // features + weight prep
    embed_kernel<<<(NN * FIN1 + B - 1) / B, B, 0, stream>>>(sid, cid, pid, stab, ctab, ptab, x0);
    wprep<<<60, B, 0, stream>>>(W1l, W1r, W2l, W2r, bt1, bt2);

    // CSR build (row_ptr derived inside csr_fill2 — no deg_hist/global scan)
    bucket_hist<<<(NE + BIN_PER - 1) / BIN_PER, B, 0, stream>>>(dst, bcnt);
    bucket_scan<<<1, 1024, 0, stream>>>(bcnt, bstart, bcur);
    bin_edges<<<(NE + BIN_PER - 1) / BIN_PER, B, 0, stream>>>(src, dst, bcur, ebuf);
    csr_fill2<<<NBUK, B, 0, stream>>>(ebuf, bstart, row_ptr, eidx);

    graph_bounds<<<(NN + B - 1) / B, B, 0, stream>>>(batch, gstart);

    // ---- layer 1 ----
    gather_agg<FIN1, false><<<(NN * 64 + B - 1) / B, B, 0, stream>>>(
        row_ptr, eidx, x0, agg, nullptr, nullptr, nullptr);
    sage_mfma<FIN1, 96, 104, false><<<NN / 64, B, 0, stream>>>(
        x0, agg, row_ptr, bt1, b1, hbuf, nullptr, nullptr, nullptr);
    bn_stats<<<(NN + 511) / 512, B, 0, stream>>>(hbuf, stats);

    // ---- layer 2 (BN1+ReLU fused into gather & A-staging) ----
    gather_agg<HID, true><<<(NN * 64 + B - 1) / B, B, 0, stream>>>(
        row_ptr, eidx, hbuf, agg, stats, g1, be1);
    sage_mfma<HID, 128, 136, true><<<NN / 64, B, 0, stream>>>(
        hbuf, agg, row_ptr, bt2, b2, h2, stats, g1, be1);
    bn_stats<<<(NN + 511) / 512, B, 0, stream>>>(h2, stats + 128);

    // ---- fused BN2+ReLU+pool+head ----
    pool_out<<<(NG * 64 + B - 1) / B, B, 0, stream>>>(h2, stats + 128, g2, be2, gstart,
                                                      Wout, bout, (float*)d_out);
}

// Round 8
// 261.417 us; speedup vs baseline: 2.2710x; 1.0965x over previous
//
#include <hip/hip_runtime.h>

#define NN 80000
#define NE 1280000
#define NG 2000
#define HID 64
#define FIN1 40
#define NBUK ((NN + 127) >> 7)             // 625 buckets of 128 nodes (NN = 625*128 exactly)
#define BIN_PER 4096
constexpr float EPS = 1e-5f;

typedef _Float16 f16;
typedef f16 f16x4 __attribute__((ext_vector_type(4)));
typedef f16 f16x8 __attribute__((ext_vector_type(8)));
typedef float f32x4 __attribute__((ext_vector_type(4)));

// ---------------- embed (f16 out): x0[n] = concat(stab, ctab, ptab) ----------
__global__ void embed16(const int* __restrict__ sid, const int* __restrict__ cid,
                        const int* __restrict__ pid,
                        const float* __restrict__ stab, const float* __restrict__ ctab,
                        const float* __restrict__ ptab, f16* __restrict__ x0) {
    int idx = blockIdx.x * 256 + threadIdx.x;   // (node, 8-feature unit)
    if (idx >= NN * 5) return;
    int n = idx / 5, u = idx - n * 5;
    const float* srcp;
    if (u < 2)      srcp = &stab[sid[n] * 16 + u * 8];
    else if (u < 4) srcp = &ctab[cid[n] * 16 + (u - 2) * 8];
    else            srcp = &ptab[pid[n] * 8];
    f16x8 o;
#pragma unroll
    for (int i = 0; i < 8; i++) o[i] = (f16)srcp[i];
    *(f16x8*)&x0[(size_t)n * FIN1 + u * 8] = o;
}

// ---------------- W prep: Bt[j][k] = [Wl;Wr]^T as f16, padded ----------------
__global__ void wprep(const float* __restrict__ W1l, const float* __restrict__ W1r,
                      const float* __restrict__ W2l, const float* __restrict__ W2r,
                      f16* __restrict__ Bt1, f16* __restrict__ Bt2) {
    int i = blockIdx.x * 256 + threadIdx.x;
    if (i < 64 * 104) {
        int j = i / 104, k = i - j * 104;
        float v = 0.f;
        if (k < 40) v = W1l[k * 64 + j];
        else if (k < 80) v = W1r[(k - 40) * 64 + j];
        Bt1[i] = (f16)v;
    }
    int i2 = i - 64 * 104;
    if (i2 >= 0 && i2 < 64 * 136) {
        int j = i2 / 136, k = i2 - j * 136;
        float v = 0.f;
        if (k < 64) v = W2l[k * 64 + j];
        else if (k < 128) v = W2r[(k - 64) * 64 + j];
        Bt2[i2] = (f16)v;
    }
}

// ---------------- bucket binning ----------------
__global__ void bucket_hist(const int* __restrict__ dst, int* __restrict__ bcnt) {
    __shared__ int lh[NBUK];
    for (int i = threadIdx.x; i < NBUK; i += 256) lh[i] = 0;
    __syncthreads();
    int e0 = blockIdx.x * BIN_PER;
    int e1 = min(e0 + BIN_PER, NE);
    for (int e = e0 + threadIdx.x; e < e1; e += 256) atomicAdd(&lh[dst[e] >> 7], 1);
    __syncthreads();
    for (int i = threadIdx.x; i < NBUK; i += 256)
        if (lh[i]) atomicAdd(&bcnt[i], lh[i]);
}

__global__ void bucket_scan(const int* __restrict__ bcnt, int* __restrict__ bstart,
                            int* __restrict__ bcur) {
    __shared__ int l[1024];
    int t = threadIdx.x;
    l[t] = (t < NBUK) ? bcnt[t] : 0;
    __syncthreads();
    for (int off = 1; off < 1024; off <<= 1) {
        int v = (t >= off) ? l[t - off] : 0;
        __syncthreads();
        l[t] += v;
        __syncthreads();
    }
    int excl = (t == 0) ? 0 : l[t - 1];
    if (t < NBUK) { bstart[t] = excl; bcur[t] = excl; }
    if (t == NBUK) bstart[NBUK] = NE;
}

__global__ void bin_edges(const int* __restrict__ src, const int* __restrict__ dst,
                          int* __restrict__ bcur, int* __restrict__ ebuf) {
    __shared__ int lh[NBUK];
    __shared__ int lbase[NBUK];
    for (int i = threadIdx.x; i < NBUK; i += 256) lh[i] = 0;
    __syncthreads();
    int e0 = blockIdx.x * BIN_PER;
    int e1 = min(e0 + BIN_PER, NE);
    for (int e = e0 + threadIdx.x; e < e1; e += 256) atomicAdd(&lh[dst[e] >> 7], 1);
    __syncthreads();
    for (int i = threadIdx.x; i < NBUK; i += 256) {
        int c = lh[i];
        lbase[i] = c ? atomicAdd(&bcur[i], c) : 0;
    }
    __syncthreads();
    for (int i = threadIdx.x; i < NBUK; i += 256) lh[i] = 0;
    __syncthreads();
    for (int e = e0 + threadIdx.x; e < e1; e += 256) {
        int d = dst[e];
        int b = d >> 7;
        int off = atomicAdd(&lh[b], 1);
        ebuf[lbase[b] + off] = (src[e] << 7) | (d & 127);
    }
}

__global__ void csr_fill2(const int* __restrict__ ebuf, const int* __restrict__ bstart,
                          int* __restrict__ row_ptr, int* __restrict__ eidx) {
    __shared__ int cnt[128];
    __shared__ int sb[128];
    __shared__ int lcur[128];
    int b = blockIdx.x;
    int t = threadIdx.x;
    int nbase = b << 7;
    if (t < 128) cnt[t] = 0;
    __syncthreads();
    int s0 = bstart[b], s1 = bstart[b + 1];
    for (int i = s0 + t; i < s1; i += 256) atomicAdd(&cnt[ebuf[i] & 127], 1);
    __syncthreads();
    if (t < 128) sb[t] = cnt[t];
    __syncthreads();
    for (int off = 1; off < 128; off <<= 1) {
        int v = (t >= off && t < 128) ? sb[t - off] : 0;
        __syncthreads();
        if (t < 128) sb[t] += v;
        __syncthreads();
    }
    if (t < 128) {
        int excl = ((t == 0) ? 0 : sb[t - 1]) + s0;
        row_ptr[nbase + t] = excl;
        lcur[t] = excl;
    }
    if (b == 0 && t == 0) row_ptr[NN] = NE;
    __syncthreads();
    for (int i = s0 + t; i < s1; i += 256) {
        int v = ebuf[i];
        int pos = atomicAdd(&lcur[v & 127], 1);
        eidx[pos] = v >> 7;
    }
}

// ---------------- gather-aggregate (f16 rows): agg[n] = sum x[s] ------------
// one wave per node; 8 groups of 8 lanes; each group one edge; f16x8 loads.
template <int F>
__global__ void gather16(const int* __restrict__ row_ptr, const int* __restrict__ eidx,
                         const f16* __restrict__ x, f16* __restrict__ agg) {
    int t = blockIdx.x * blockDim.x + threadIdx.x;
    int n = t >> 6;
    int lane = threadIdx.x & 63;
    if (n >= NN) return;
    int grp = lane >> 3;        // group 0..7
    int fl = (lane & 7) * 8;    // feature base
    bool active = fl < F;
    int beg = row_ptr[n], end = row_ptr[n + 1];
    float ac[8];
#pragma unroll
    for (int i = 0; i < 8; i++) ac[i] = 0.f;
    for (int j0 = beg; j0 < end; j0 += 64) {
        int cnt = min(64, end - j0);
        int myid = (j0 + lane < end) ? eidx[j0 + lane] : 0;
        int steps = (cnt + 7) >> 3;
        for (int u = 0; u < steps; u++) {
            int e = u * 8 + grp;
            int s = __shfl(myid, e);
            if (e < cnt && active) {
                f16x8 v = *(const f16x8*)&x[(size_t)s * F + fl];
#pragma unroll
                for (int i = 0; i < 8; i++) ac[i] += (float)v[i];
            }
        }
    }
#pragma unroll
    for (int m = 8; m <= 32; m <<= 1) {
#pragma unroll
        for (int i = 0; i < 8; i++) ac[i] += __shfl_xor(ac[i], m);
    }
    if (lane < 8 && active) {
        f16x8 o;
#pragma unroll
        for (int i = 0; i < 8; i++) o[i] = (f16)ac[i];
        *(f16x8*)&agg[(size_t)n * F + fl] = o;
    }
}

// ---------------- MFMA SAGE linear: h = [agg/deg | x] @ [Wl;Wr] + b ---------
// block = 64 nodes, 4 waves. A staged f16 in LDS; B from prepped Bt image.
template <int FIN, int KTOT, int KP>
__launch_bounds__(256)
__global__ void sage_mfma(const f16* __restrict__ x, const f16* __restrict__ agg,
                          const int* __restrict__ row_ptr, const f16* __restrict__ Btg,
                          const float* __restrict__ bias, f16* __restrict__ h) {
    __shared__ f16 Asm[64 * KP];
    __shared__ f16 Bsm[64 * KP];
    __shared__ float sinv[64];

    int tid = threadIdx.x;
    int n0 = blockIdx.x * 64;

    if (tid < 64) {
        int n = n0 + tid;
        int deg = row_ptr[n + 1] - row_ptr[n];
        sinv[tid] = 1.0f / (float)max(deg, 1);
    }
    __syncthreads();

    constexpr int UA = FIN / 8;     // f16x8 units of xa (and of xr)
    constexpr int UT = KP / 8;      // units per row
    for (int i = tid; i < 64 * UT; i += 256) {
        int r = i / UT, u = i - r * UT;
        f16x8 o;
        if (u < UA) {               // xa = agg/deg
            f16x8 va = *(const f16x8*)&agg[(size_t)(n0 + r) * FIN + u * 8];
            float inv = sinv[r];
#pragma unroll
            for (int k = 0; k < 8; k++) o[k] = (f16)((float)va[k] * inv);
        } else if (u < 2 * UA) {    // xr = x (straight copy)
            o = *(const f16x8*)&x[(size_t)(n0 + r) * FIN + (u - UA) * 8];
        } else {                    // zero pad
#pragma unroll
            for (int k = 0; k < 8; k++) o[k] = (f16)0.f;
        }
        *(f16x8*)&Asm[r * KP + u * 8] = o;
    }
    const int NU4 = 64 * KP * 2 / 16;
    for (int i = tid; i < NU4; i += 256)
        ((uint4*)Bsm)[i] = ((const uint4*)Btg)[i];
    __syncthreads();

    int w = tid >> 6;
    int l = tid & 63;
    int jloc = l & 15;
    int kg = l >> 4;
    int rbase = w * 16;

    f32x4 acc[4];
#pragma unroll
    for (int jt = 0; jt < 4; jt++) {
        float bj = bias[jt * 16 + jloc];
        acc[jt] = (f32x4){bj, bj, bj, bj};
    }
#pragma unroll
    for (int kk = 0; kk < KTOT / 32; kk++) {
        f16x8 af = *(const f16x8*)&Asm[(rbase + jloc) * KP + kk * 32 + kg * 8];
#pragma unroll
        for (int jt = 0; jt < 4; jt++) {
            f16x8 bf = *(const f16x8*)&Bsm[(jt * 16 + jloc) * KP + kk * 32 + kg * 8];
            acc[jt] = __builtin_amdgcn_mfma_f32_16x16x32_f16(af, bf, acc[jt], 0, 0, 0);
        }
    }
#pragma unroll
    for (int jt = 0; jt < 4; jt++) {
#pragma unroll
        for (int reg = 0; reg < 4; reg++) {
            int n = n0 + rbase + kg * 4 + reg;
            h[(size_t)n * HID + jt * 16 + jloc] = (f16)acc[jt][reg];
        }
    }
}

// ---------------- BN stats (f16 in): stats[f]=sum, stats[64+f]=sumsq --------
__global__ void bn_stats16(const f16* __restrict__ h, float* __restrict__ stats) {
    const int NPB = 512;
    int f = threadIdx.x & 63;
    int r = threadIdx.x >> 6;
    int n0 = blockIdx.x * NPB;
    int nend = min(n0 + NPB, NN);
    float s = 0.f, ss = 0.f;
    for (int n = n0 + r; n < nend; n += 4) {
        float v = (float)h[(size_t)n * HID + f];
        s += v;
        ss += v * v;
    }
    __shared__ float ls[4][64];
    __shared__ float lss[4][64];
    ls[r][f] = s;
    lss[r][f] = ss;
    __syncthreads();
    if (r == 0) {
        s = ls[0][f] + ls[1][f] + ls[2][f] + ls[3][f];
        ss = lss[0][f] + lss[1][f] + lss[2][f] + lss[3][f];
        atomicAdd(&stats[f], s);
        atomicAdd(&stats[64 + f], ss);
    }
}

// ---------------- BN apply + ReLU, in-place on f16 ----------------
__global__ void bn_apply16(f16* __restrict__ h, const float* __restrict__ stats,
                           const float* __restrict__ g, const float* __restrict__ be) {
    __shared__ float ssc[64], ssh[64];
    int tid = threadIdx.x;
    if (tid < 64) {
        const float invn = 1.0f / (float)NN;
        float m = stats[tid] * invn;
        float var = stats[64 + tid] * invn - m * m;
        float sc = g[tid] * __frsqrt_rn(var + EPS);
        ssc[tid] = sc;
        ssh[tid] = be[tid] - m * sc;
    }
    __syncthreads();
    int idx = blockIdx.x * 256 + tid;      // unit of 8 f16
    if (idx >= NN * 8) return;
    int f = (idx & 7) * 8;
    f16x8 v = *(f16x8*)&h[(size_t)idx * 8];
    f16x8 o;
#pragma unroll
    for (int i = 0; i < 8; i++) {
        float xv = (float)v[i];
        o[i] = (f16)fmaxf(fmaf(xv, ssc[f + i], ssh[f + i]), 0.f);
    }
    *(f16x8*)&h[(size_t)idx * 8] = o;
}

// ---------------- graph boundaries from sorted batch ----------------
__global__ void graph_bounds(const int* __restrict__ batch, int* __restrict__ gstart) {
    int n = blockIdx.x * blockDim.x + threadIdx.x;
    if (n >= NN) return;
    int cur = batch[n];
    int prev = (n == 0) ? -1 : batch[n - 1];
    for (int g = prev + 1; g <= cur; g++) gstart[g] = n;
    if (n == NN - 1) {
        for (int g = cur + 1; g <= NG; g++) gstart[g] = NN;
    }
}

// ---------------- fused BN2+ReLU + mean-pool + output GEMV ----------------
__global__ void pool_out(const f16* __restrict__ h, const float* __restrict__ stats2,
                         const float* __restrict__ g2, const float* __restrict__ be2,
                         const int* __restrict__ gstart,
                         const float* __restrict__ Wout, const float* __restrict__ bout,
                         float* __restrict__ out) {
    int w = (blockIdx.x * blockDim.x + threadIdx.x) >> 6;
    int f = threadIdx.x & 63;
    if (w >= NG) return;
    const float invn = 1.0f / (float)NN;
    float m = stats2[f] * invn;
    float var = stats2[64 + f] * invn - m * m;
    float sc = g2[f] / sqrtf(var + EPS);
    float sh = be2[f] - m * sc;
    int n0 = gstart[w], n1 = gstart[w + 1];
    float acc = 0.f;
    for (int n = n0; n < n1; n++) {
        float v = fmaf((float)h[(size_t)n * HID + f], sc, sh);
        acc += fmaxf(v, 0.0f);
    }
    float inv = 1.0f / (float)max(n1 - n0, 1);
    float p = acc * inv;
    float a0 = p * Wout[f * 2 + 0];
    float a1 = p * Wout[f * 2 + 1];
#pragma unroll
    for (int mm = 1; mm < 64; mm <<= 1) {
        a0 += __shfl_xor(a0, mm);
        a1 += __shfl_xor(a1, mm);
    }
    if (f == 0) {
        out[w * 2 + 0] = a0 + bout[0];
        out[w * 2 + 1] = a1 + bout[1];
    }
}

extern "C" void kernel_launch(void* const* d_in, const int* in_sizes, int n_in,
                              void* d_out, int out_size, void* d_ws, size_t ws_size,
                              hipStream_t stream) {
    const int* sid = (const int*)d_in[0];
    const int* cid = (const int*)d_in[1];
    const int* pid = (const int*)d_in[2];
    const int* ei = (const int*)d_in[3];
    const int* batch = (const int*)d_in[4];
    const float* stab = (const float*)d_in[6];
    const float* ctab = (const float*)d_in[7];
    const float* ptab = (const float*)d_in[8];
    const float* W1l = (const float*)d_in[9];
    const float* b1 = (const float*)d_in[10];
    const float* W1r = (const float*)d_in[11];
    const float* g1 = (const float*)d_in[12];
    const float* be1 = (const float*)d_in[13];
    const float* W2l = (const float*)d_in[14];
    const float* b2 = (const float*)d_in[15];
    const float* W2r = (const float*)d_in[16];
    const float* g2 = (const float*)d_in[17];
    const float* be2 = (const float*)d_in[18];
    const float* Wout = (const float*)d_in[19];
    const float* bout = (const float*)d_in[20];

    const int* src = ei;
    const int* dst = ei + NE;

    char* p = (char*)d_ws;
    f16* x0 = (f16*)p;        p += (size_t)NN * FIN1 * 2;      // 6.4 MB
    f16* agg = (f16*)p;       p += (size_t)NN * HID * 2;       // 10.24 MB
    f16* h1 = (f16*)p;        p += (size_t)NN * HID * 2;
    f16* h2 = (f16*)p;        p += (size_t)NN * HID * 2;
    float* stats = (float*)p; p += 256 * 4;
    f16* bt1 = (f16*)p;       p += 64 * 104 * 2;
    f16* bt2 = (f16*)p;       p += 64 * 136 * 2;
    int* row_ptr = (int*)p;   p += (NN + 1) * 4;
    int* gstart = (int*)p;    p += (NG + 1) * 4;
    int* bcnt = (int*)p;      p += NBUK * 4;
    int* bstart = (int*)p;    p += (NBUK + 1) * 4;
    int* bcur = (int*)p;      p += NBUK * 4;
    int* eidx = (int*)p;      p += (size_t)NE * 4;
    int* ebuf = (int*)p;      p += (size_t)NE * 4;

    hipMemsetAsync(bcnt, 0, NBUK * sizeof(int), stream);
    hipMemsetAsync(stats, 0, 256 * sizeof(float), stream);

    const int B = 256;

    // features + weight prep
    embed16<<<(NN * 5 + B - 1) / B, B, 0, stream>>>(sid, cid, pid, stab, ctab, ptab, x0);
    wprep<<<60, B, 0, stream>>>(W1l, W1r, W2l, W2r, bt1, bt2);

    // CSR build
    bucket_hist<<<(NE + BIN_PER - 1) / BIN_PER, B, 0, stream>>>(dst, bcnt);
    bucket_scan<<<1, 1024, 0, stream>>>(bcnt, bstart, bcur);
    bin_edges<<<(NE + BIN_PER - 1) / BIN_PER, B, 0, stream>>>(src, dst, bcur, ebuf);
    csr_fill2<<<NBUK, B, 0, stream>>>(ebuf, bstart, row_ptr, eidx);

    graph_bounds<<<(NN + B - 1) / B, B, 0, stream>>>(batch, gstart);

    // ---- layer 1 ----
    gather16<FIN1><<<(NN * 64 + B - 1) / B, B, 0, stream>>>(row_ptr, eidx, x0, agg);
    sage_mfma<FIN1, 96, 104><<<NN / 64, B, 0, stream>>>(x0, agg, row_ptr, bt1, b1, h1);
    bn_stats16<<<(NN + 511) / 512, B, 0, stream>>>(h1, stats);
    bn_apply16<<<(NN * 8 + B - 1) / B, B, 0, stream>>>(h1, stats, g1, be1);

    // ---- layer 2 ----
    gather16<HID><<<(NN * 64 + B - 1) / B, B, 0, stream>>>(row_ptr, eidx, h1, agg);
    sage_mfma<HID, 128, 136><<<NN / 64, B, 0, stream>>>(h1, agg, row_ptr, bt2, b2, h2);
    bn_stats16<<<(NN + 511) / 512, B, 0, stream>>>(h2, stats + 128);

    // ---- fused BN2+ReLU+pool+head ----
    pool_out<<<(NG * 64 + B - 1) / B, B, 0, stream>>>(h2, stats + 128, g2, be2, gstart,
                                                      Wout, bout, (float*)d_out);
}

// Round 9
// 249.404 us; speedup vs baseline: 2.3804x; 1.0482x over previous
//
#include <hip/hip_runtime.h>

#define NN 80000
#define NE 1280000
#define NG 2000
#define HID 64
#define FIN1 40
#define BSZ 256                          // bucket size in nodes
#define NBUK ((NN + BSZ - 1) / BSZ)      // 313 buckets
#define NBS 320                          // padded row stride for bhist/lbase
#define EB 8192                          // edges per binning block
#define NBB ((NE + EB - 1) / EB)         // 157 blocks
constexpr float EPS = 1e-5f;

typedef _Float16 f16;
typedef f16 f16x8 __attribute__((ext_vector_type(8)));
typedef float f32x4 __attribute__((ext_vector_type(4)));

// ---------------- setup: ids pack | wprep | graph bounds | f16 tables -------
// region A: ids[n] = sid | cid<<4 | pid<<8              (313 blocks)
// region B: Bt1/Bt2 f16 transposed weights              (60 blocks)
// region C: graph boundaries from sorted batch          (313 blocks)
// region D: stab/ctab/ptab -> f16                       (34 blocks)
__global__ void setup(const int* __restrict__ sid, const int* __restrict__ cid,
                      const int* __restrict__ pid, const int* __restrict__ batch,
                      const float* __restrict__ stab, const float* __restrict__ ctab,
                      const float* __restrict__ ptab,
                      const float* __restrict__ W1l, const float* __restrict__ W1r,
                      const float* __restrict__ W2l, const float* __restrict__ W2r,
                      int* __restrict__ ids, f16* __restrict__ Bt1, f16* __restrict__ Bt2,
                      int* __restrict__ gstart,
                      f16* __restrict__ stab16, f16* __restrict__ ctab16,
                      f16* __restrict__ ptab16) {
    int bid = blockIdx.x;
    int tid = threadIdx.x;
    if (bid < 313) {                       // A: ids
        int n = bid * 256 + tid;
        if (n < NN) ids[n] = sid[n] | (cid[n] << 4) | (pid[n] << 8);
    } else if (bid < 373) {                // B: wprep
        int i = (bid - 313) * 256 + tid;
        if (i < 64 * 104) {
            int j = i / 104, k = i - j * 104;
            float v = 0.f;
            if (k < 40) v = W1l[k * 64 + j];
            else if (k < 80) v = W1r[(k - 40) * 64 + j];
            Bt1[i] = (f16)v;
        }
        int i2 = i - 64 * 104;
        if (i2 >= 0 && i2 < 64 * 136) {
            int j = i2 / 136, k = i2 - j * 136;
            float v = 0.f;
            if (k < 64) v = W2l[k * 64 + j];
            else if (k < 128) v = W2r[(k - 64) * 64 + j];
            Bt2[i2] = (f16)v;
        }
    } else if (bid < 686) {                // C: graph bounds
        int n = (bid - 373) * 256 + tid;
        if (n >= NN) return;
        int cur = batch[n];
        int prev = (n == 0) ? -1 : batch[n - 1];
        for (int g = prev + 1; g <= cur; g++) gstart[g] = n;
        if (n == NN - 1)
            for (int g = cur + 1; g <= NG; g++) gstart[g] = NN;
    } else {                               // D: f16 tables
        int i = (bid - 686) * 256 + tid;
        if (i < 256) stab16[i] = (f16)stab[i];
        else if (i < 512) ctab16[i - 256] = (f16)ctab[i - 256];
        else if (i < 512 + 8192) ptab16[i - 512] = (f16)ptab[i - 512];
    }
}

// ---------------- CSR build ----------------
// per-block partial histograms (no global atomics, no memset needed)
__global__ void khist(const int* __restrict__ dst, int* __restrict__ bhist) {
    __shared__ int lh[NBUK];
    for (int i = threadIdx.x; i < NBUK; i += 256) lh[i] = 0;
    __syncthreads();
    int e0 = blockIdx.x * EB, e1 = min(e0 + EB, NE);
    for (int e = e0 + threadIdx.x; e < e1; e += 256) atomicAdd(&lh[dst[e] >> 8], 1);
    __syncthreads();
    for (int i = threadIdx.x; i < NBUK; i += 256) bhist[blockIdx.x * NBS + i] = lh[i];
}

// column sums -> bucket scan -> 2D per-(block,bucket) bases
__global__ void kscan(const int* __restrict__ bhist, int* __restrict__ bstart,
                      int* __restrict__ lbase_all) {
    __shared__ int l[512];
    int t = threadIdx.x;
    int total = 0;
    if (t < NBUK)
        for (int blk = 0; blk < NBB; blk++) total += bhist[blk * NBS + t];
    l[t] = (t < NBUK) ? total : 0;
    __syncthreads();
    for (int off = 1; off < 512; off <<= 1) {
        int v = (t >= off) ? l[t - off] : 0;
        __syncthreads();
        l[t] += v;
        __syncthreads();
    }
    int excl = (t == 0) ? 0 : l[t - 1];
    if (t < NBUK) {
        bstart[t] = excl;
        int run = excl;
        for (int blk = 0; blk < NBB; blk++) {
            lbase_all[blk * NBS + t] = run;
            run += bhist[blk * NBS + t];
        }
    }
    if (t == NBUK) bstart[NBUK] = NE;
}

// single-pass placement into pre-reserved per-(block,bucket) ranges
__global__ void kbin(const int* __restrict__ src, const int* __restrict__ dst,
                     const int* __restrict__ lbase_all, int* __restrict__ ebuf) {
    __shared__ int lcur[NBUK];
    for (int i = threadIdx.x; i < NBUK; i += 256) lcur[i] = lbase_all[blockIdx.x * NBS + i];
    __syncthreads();
    int e0 = blockIdx.x * EB, e1 = min(e0 + EB, NE);
    for (int e = e0 + threadIdx.x; e < e1; e += 256) {
        int d = dst[e];
        int off = atomicAdd(&lcur[d >> 8], 1);
        ebuf[off] = (src[e] << 8) | (d & 255);
    }
}

// one block per bucket: local hist -> scan -> row_ptr + eidx fill (16KB window)
__global__ void kfill(const int* __restrict__ ebuf, const int* __restrict__ bstart,
                      int* __restrict__ row_ptr, int* __restrict__ eidx) {
    __shared__ int cnt[BSZ];
    __shared__ int sb[BSZ];
    __shared__ int lcur[BSZ];
    int b = blockIdx.x, t = threadIdx.x;
    int nbase = b << 8;
    cnt[t] = 0;
    __syncthreads();
    int s0 = bstart[b], s1 = bstart[b + 1];
    for (int i = s0 + t; i < s1; i += 256) atomicAdd(&cnt[ebuf[i] & 255], 1);
    __syncthreads();
    sb[t] = cnt[t];
    __syncthreads();
    for (int off = 1; off < BSZ; off <<= 1) {
        int v = (t >= off) ? sb[t - off] : 0;
        __syncthreads();
        sb[t] += v;
        __syncthreads();
    }
    int excl = ((t == 0) ? 0 : sb[t - 1]) + s0;
    int n = nbase + t;
    if (n < NN) row_ptr[n] = excl;
    lcur[t] = excl;
    if (b == 0 && t == 0) row_ptr[NN] = NE;
    __syncthreads();
    for (int i = s0 + t; i < s1; i += 256) {
        int v = ebuf[i];
        int pos = atomicAdd(&lcur[v & 255], 1);
        eidx[pos] = v >> 8;
    }
}

// ---------------- layer-1 gather via packed ids + L1-hot f16 tables ---------
__global__ void gather1(const int* __restrict__ row_ptr, const int* __restrict__ eidx,
                        const int* __restrict__ ids,
                        const f16* __restrict__ stab16, const f16* __restrict__ ctab16,
                        const f16* __restrict__ ptab16, f16* __restrict__ agg) {
    int tt = blockIdx.x * 256 + threadIdx.x;
    int n = tt >> 6;
    int lane = threadIdx.x & 63;
    if (n >= NN) return;
    int grp = lane >> 3, li = lane & 7;
    int beg = row_ptr[n], end = row_ptr[n + 1];
    float ac[8];
#pragma unroll
    for (int i = 0; i < 8; i++) ac[i] = 0.f;
    for (int j0 = beg; j0 < end; j0 += 64) {
        int cnt = min(64, end - j0);
        int myid = (j0 + lane < end) ? eidx[j0 + lane] : 0;
        int steps = (cnt + 7) >> 3;
        for (int u = 0; u < steps; u++) {
            int e = u * 8 + grp;
            int s = __shfl(myid, e);
            if (e < cnt && li < 5) {
                int id = ids[s];
                const f16* rowp;
                if (li < 2)      rowp = &stab16[(id & 15) * 16 + li * 8];
                else if (li < 4) rowp = &ctab16[((id >> 4) & 15) * 16 + (li - 2) * 8];
                else             rowp = &ptab16[(id >> 8) * 8];
                f16x8 v = *(const f16x8*)rowp;
#pragma unroll
                for (int i = 0; i < 8; i++) ac[i] += (float)v[i];
            }
        }
    }
#pragma unroll
    for (int m = 8; m <= 32; m <<= 1) {
#pragma unroll
        for (int i = 0; i < 8; i++) ac[i] += __shfl_xor(ac[i], m);
    }
    if (lane < 5) {
        f16x8 o;
#pragma unroll
        for (int i = 0; i < 8; i++) o[i] = (f16)ac[i];
        *(f16x8*)&agg[(size_t)n * FIN1 + lane * 8] = o;
    }
}

// ---------------- layer-2 gather (f16 rows) ----------------
template <int F>
__global__ void gather16(const int* __restrict__ row_ptr, const int* __restrict__ eidx,
                         const f16* __restrict__ x, f16* __restrict__ agg) {
    int tt = blockIdx.x * 256 + threadIdx.x;
    int n = tt >> 6;
    int lane = threadIdx.x & 63;
    if (n >= NN) return;
    int grp = lane >> 3;
    int fl = (lane & 7) * 8;
    bool active = fl < F;
    int beg = row_ptr[n], end = row_ptr[n + 1];
    float ac[8];
#pragma unroll
    for (int i = 0; i < 8; i++) ac[i] = 0.f;
    for (int j0 = beg; j0 < end; j0 += 64) {
        int cnt = min(64, end - j0);
        int myid = (j0 + lane < end) ? eidx[j0 + lane] : 0;
        int steps = (cnt + 7) >> 3;
        for (int u = 0; u < steps; u++) {
            int e = u * 8 + grp;
            int s = __shfl(myid, e);
            if (e < cnt && active) {
                f16x8 v = *(const f16x8*)&x[(size_t)s * F + fl];
#pragma unroll
                for (int i = 0; i < 8; i++) ac[i] += (float)v[i];
            }
        }
    }
#pragma unroll
    for (int m = 8; m <= 32; m <<= 1) {
#pragma unroll
        for (int i = 0; i < 8; i++) ac[i] += __shfl_xor(ac[i], m);
    }
    if (lane < 8 && active) {
        f16x8 o;
#pragma unroll
        for (int i = 0; i < 8; i++) o[i] = (f16)ac[i];
        *(f16x8*)&agg[(size_t)n * F + fl] = o;
    }
}

// ---------------- MFMA layer 1: h1 = [agg/deg | x(ids)] @ Bt1 + b -----------
__launch_bounds__(256)
__global__ void sage_mfma1(const int* __restrict__ ids, const f16* __restrict__ agg,
                           const int* __restrict__ row_ptr,
                           const f16* __restrict__ stab16, const f16* __restrict__ ctab16,
                           const f16* __restrict__ ptab16,
                           const f16* __restrict__ Btg, const float* __restrict__ bias,
                           f16* __restrict__ h) {
    const int KTOT = 96, KP = 104, UT = KP / 8;   // 13 units/row
    __shared__ f16 Asm[64 * KP];
    __shared__ f16 Bsm[64 * KP];
    __shared__ float sinv[64];

    int tid = threadIdx.x;
    int n0 = blockIdx.x * 64;
    if (tid < 64) {
        int n = n0 + tid;
        int deg = row_ptr[n + 1] - row_ptr[n];
        sinv[tid] = 1.0f / (float)max(deg, 1);
    }
    __syncthreads();

    for (int i = tid; i < 64 * UT; i += 256) {
        int r = i / UT, u = i - r * UT;
        f16x8 o;
        if (u < 5) {                    // xa = agg/deg
            f16x8 va = *(const f16x8*)&agg[(size_t)(n0 + r) * FIN1 + u * 8];
            float inv = sinv[r];
#pragma unroll
            for (int k = 0; k < 8; k++) o[k] = (f16)((float)va[k] * inv);
        } else if (u < 10) {            // xr from tables
            int id = ids[n0 + r];
            int c = u - 5;
            const f16* rowp;
            if (c < 2)      rowp = &stab16[(id & 15) * 16 + c * 8];
            else if (c < 4) rowp = &ctab16[((id >> 4) & 15) * 16 + (c - 2) * 8];
            else            rowp = &ptab16[(id >> 8) * 8];
            o = *(const f16x8*)rowp;
        } else {
#pragma unroll
            for (int k = 0; k < 8; k++) o[k] = (f16)0.f;
        }
        *(f16x8*)&Asm[r * KP + u * 8] = o;
    }
    for (int i = tid; i < 64 * KP * 2 / 16; i += 256)
        ((uint4*)Bsm)[i] = ((const uint4*)Btg)[i];
    __syncthreads();

    int w = tid >> 6, l = tid & 63;
    int jloc = l & 15, kg = l >> 4;
    int rbase = w * 16;
    f32x4 acc[4];
#pragma unroll
    for (int jt = 0; jt < 4; jt++) {
        float bj = bias[jt * 16 + jloc];
        acc[jt] = (f32x4){bj, bj, bj, bj};
    }
#pragma unroll
    for (int kk = 0; kk < KTOT / 32; kk++) {
        f16x8 af = *(const f16x8*)&Asm[(rbase + jloc) * KP + kk * 32 + kg * 8];
#pragma unroll
        for (int jt = 0; jt < 4; jt++) {
            f16x8 bf = *(const f16x8*)&Bsm[(jt * 16 + jloc) * KP + kk * 32 + kg * 8];
            acc[jt] = __builtin_amdgcn_mfma_f32_16x16x32_f16(af, bf, acc[jt], 0, 0, 0);
        }
    }
#pragma unroll
    for (int jt = 0; jt < 4; jt++)
#pragma unroll
        for (int reg = 0; reg < 4; reg++) {
            int n = n0 + rbase + kg * 4 + reg;
            h[(size_t)n * HID + jt * 16 + jloc] = (f16)acc[jt][reg];
        }
}

// ---------------- MFMA layer 2: h2 = [agg/deg | h1] @ Bt2 + b ---------------
__launch_bounds__(256)
__global__ void sage_mfma2(const f16* __restrict__ x, const f16* __restrict__ agg,
                           const int* __restrict__ row_ptr, const f16* __restrict__ Btg,
                           const float* __restrict__ bias, f16* __restrict__ h) {
    const int FIN = 64, KTOT = 128, KP = 136, UT = KP / 8;   // 17 units/row
    __shared__ f16 Asm[64 * KP];
    __shared__ f16 Bsm[64 * KP];
    __shared__ float sinv[64];

    int tid = threadIdx.x;
    int n0 = blockIdx.x * 64;
    if (tid < 64) {
        int n = n0 + tid;
        int deg = row_ptr[n + 1] - row_ptr[n];
        sinv[tid] = 1.0f / (float)max(deg, 1);
    }
    __syncthreads();

    for (int i = tid; i < 64 * UT; i += 256) {
        int r = i / UT, u = i - r * UT;
        f16x8 o;
        if (u < 8) {
            f16x8 va = *(const f16x8*)&agg[(size_t)(n0 + r) * FIN + u * 8];
            float inv = sinv[r];
#pragma unroll
            for (int k = 0; k < 8; k++) o[k] = (f16)((float)va[k] * inv);
        } else if (u < 16) {
            o = *(const f16x8*)&x[(size_t)(n0 + r) * FIN + (u - 8) * 8];
        } else {
#pragma unroll
            for (int k = 0; k < 8; k++) o[k] = (f16)0.f;
        }
        *(f16x8*)&Asm[r * KP + u * 8] = o;
    }
    for (int i = tid; i < 64 * KP * 2 / 16; i += 256)
        ((uint4*)Bsm)[i] = ((const uint4*)Btg)[i];
    __syncthreads();

    int w = tid >> 6, l = tid & 63;
    int jloc = l & 15, kg = l >> 4;
    int rbase = w * 16;
    f32x4 acc[4];
#pragma unroll
    for (int jt = 0; jt < 4; jt++) {
        float bj = bias[jt * 16 + jloc];
        acc[jt] = (f32x4){bj, bj, bj, bj};
    }
#pragma unroll
    for (int kk = 0; kk < KTOT / 32; kk++) {
        f16x8 af = *(const f16x8*)&Asm[(rbase + jloc) * KP + kk * 32 + kg * 8];
#pragma unroll
        for (int jt = 0; jt < 4; jt++) {
            f16x8 bf = *(const f16x8*)&Bsm[(jt * 16 + jloc) * KP + kk * 32 + kg * 8];
            acc[jt] = __builtin_amdgcn_mfma_f32_16x16x32_f16(af, bf, acc[jt], 0, 0, 0);
        }
    }
#pragma unroll
    for (int jt = 0; jt < 4; jt++)
#pragma unroll
        for (int reg = 0; reg < 4; reg++) {
            int n = n0 + rbase + kg * 4 + reg;
            h[(size_t)n * HID + jt * 16 + jloc] = (f16)acc[jt][reg];
        }
}

// ---------------- BN stats (f16 in) ----------------
__global__ void bn_stats16(const f16* __restrict__ h, float* __restrict__ stats) {
    const int NPB = 512;
    int f = threadIdx.x & 63;
    int r = threadIdx.x >> 6;
    int n0 = blockIdx.x * NPB;
    int nend = min(n0 + NPB, NN);
    float s = 0.f, ss = 0.f;
    for (int n = n0 + r; n < nend; n += 4) {
        float v = (float)h[(size_t)n * HID + f];
        s += v;
        ss += v * v;
    }
    __shared__ float ls[4][64];
    __shared__ float lss[4][64];
    ls[r][f] = s;
    lss[r][f] = ss;
    __syncthreads();
    if (r == 0) {
        s = ls[0][f] + ls[1][f] + ls[2][f] + ls[3][f];
        ss = lss[0][f] + lss[1][f] + lss[2][f] + lss[3][f];
        atomicAdd(&stats[f], s);
        atomicAdd(&stats[64 + f], ss);
    }
}

// ---------------- BN apply + ReLU, in-place f16 ----------------
__global__ void bn_apply16(f16* __restrict__ h, const float* __restrict__ stats,
                           const float* __restrict__ g, const float* __restrict__ be) {
    __shared__ float ssc[64], ssh[64];
    int tid = threadIdx.x;
    if (tid < 64) {
        const float invn = 1.0f / (float)NN;
        float m = stats[tid] * invn;
        float var = stats[64 + tid] * invn - m * m;
        float sc = g[tid] * __frsqrt_rn(var + EPS);
        ssc[tid] = sc;
        ssh[tid] = be[tid] - m * sc;
    }
    __syncthreads();
    int idx = blockIdx.x * 256 + tid;
    if (idx >= NN * 8) return;
    int f = (idx & 7) * 8;
    f16x8 v = *(f16x8*)&h[(size_t)idx * 8];
    f16x8 o;
#pragma unroll
    for (int i = 0; i < 8; i++) {
        float xv = (float)v[i];
        o[i] = (f16)fmaxf(fmaf(xv, ssc[f + i], ssh[f + i]), 0.f);
    }
    *(f16x8*)&h[(size_t)idx * 8] = o;
}

// ---------------- fused BN2+ReLU + mean-pool + output GEMV ----------------
__global__ void pool_out(const f16* __restrict__ h, const float* __restrict__ stats2,
                         const float* __restrict__ g2, const float* __restrict__ be2,
                         const int* __restrict__ gstart,
                         const float* __restrict__ Wout, const float* __restrict__ bout,
                         float* __restrict__ out) {
    int w = (blockIdx.x * blockDim.x + threadIdx.x) >> 6;
    int f = threadIdx.x & 63;
    if (w >= NG) return;
    const float invn = 1.0f / (float)NN;
    float m = stats2[f] * invn;
    float var = stats2[64 + f] * invn - m * m;
    float sc = g2[f] / sqrtf(var + EPS);
    float sh = be2[f] - m * sc;
    int n0 = gstart[w], n1 = gstart[w + 1];
    float acc = 0.f;
    for (int n = n0; n < n1; n++) {
        float v = fmaf((float)h[(size_t)n * HID + f], sc, sh);
        acc += fmaxf(v, 0.0f);
    }
    float inv = 1.0f / (float)max(n1 - n0, 1);
    float p = acc * inv;
    float a0 = p * Wout[f * 2 + 0];
    float a1 = p * Wout[f * 2 + 1];
#pragma unroll
    for (int mm = 1; mm < 64; mm <<= 1) {
        a0 += __shfl_xor(a0, mm);
        a1 += __shfl_xor(a1, mm);
    }
    if (f == 0) {
        out[w * 2 + 0] = a0 + bout[0];
        out[w * 2 + 1] = a1 + bout[1];
    }
}

extern "C" void kernel_launch(void* const* d_in, const int* in_sizes, int n_in,
                              void* d_out, int out_size, void* d_ws, size_t ws_size,
                              hipStream_t stream) {
    const int* sid = (const int*)d_in[0];
    const int* cid = (const int*)d_in[1];
    const int* pid = (const int*)d_in[2];
    const int* ei = (const int*)d_in[3];
    const int* batch = (const int*)d_in[4];
    const float* stab = (const float*)d_in[6];
    const float* ctab = (const float*)d_in[7];
    const float* ptab = (const float*)d_in[8];
    const float* W1l = (const float*)d_in[9];
    const float* b1 = (const float*)d_in[10];
    const float* W1r = (const float*)d_in[11];
    const float* g1 = (const float*)d_in[12];
    const float* be1 = (const float*)d_in[13];
    const float* W2l = (const float*)d_in[14];
    const float* b2 = (const float*)d_in[15];
    const float* W2r = (const float*)d_in[16];
    const float* g2 = (const float*)d_in[17];
    const float* be2 = (const float*)d_in[18];
    const float* Wout = (const float*)d_in[19];
    const float* bout = (const float*)d_in[20];

    const int* src = ei;
    const int* dst = ei + NE;

    char* p = (char*)d_ws;
    f16* agg = (f16*)p;        p += (size_t)NN * HID * 2;   // layer1 uses stride 40
    f16* h1 = (f16*)p;         p += (size_t)NN * HID * 2;
    f16* h2 = (f16*)p;         p += (size_t)NN * HID * 2;
    f16* bt1 = (f16*)p;        p += 64 * 104 * 2;
    f16* bt2 = (f16*)p;        p += 64 * 136 * 2;
    f16* stab16 = (f16*)p;     p += 256 * 2;
    f16* ctab16 = (f16*)p;     p += 256 * 2;
    f16* ptab16 = (f16*)p;     p += 8192 * 2;
    float* stats = (float*)p;  p += 256 * 4;
    int* ids = (int*)p;        p += (size_t)NN * 4;
    int* row_ptr = (int*)p;    p += (NN + 1) * 4;
    int* gstart = (int*)p;     p += (NG + 1) * 4;
    int* bhist = (int*)p;      p += (size_t)NBB * NBS * 4;
    int* lbase = (int*)p;      p += (size_t)NBB * NBS * 4;
    int* bstart = (int*)p;     p += (NBUK + 1) * 4;
    int* eidx = (int*)p;       p += (size_t)NE * 4;
    int* ebuf = (int*)p;       p += (size_t)NE * 4;

    hipMemsetAsync(stats, 0, 256 * sizeof(float), stream);

    const int B = 256;

    // fused setup: ids | weight prep | graph bounds | f16 tables
    setup<<<720, B, 0, stream>>>(sid, cid, pid, batch, stab, ctab, ptab,
                                 W1l, W1r, W2l, W2r,
                                 ids, bt1, bt2, gstart, stab16, ctab16, ptab16);

    // CSR build: partial hists -> scan(+2D bases) -> single-pass bin -> fill
    khist<<<NBB, B, 0, stream>>>(dst, bhist);
    kscan<<<1, 512, 0, stream>>>(bhist, bstart, lbase);
    kbin<<<NBB, B, 0, stream>>>(src, dst, lbase, ebuf);
    kfill<<<NBUK, B, 0, stream>>>(ebuf, bstart, row_ptr, eidx);

    // ---- layer 1 ----
    gather1<<<(NN * 64 + B - 1) / B, B, 0, stream>>>(row_ptr, eidx, ids,
                                                     stab16, ctab16, ptab16, agg);
    sage_mfma1<<<NN / 64, B, 0, stream>>>(ids, agg, row_ptr, stab16, ctab16, ptab16,
                                          bt1, b1, h1);
    bn_stats16<<<(NN + 511) / 512, B, 0, stream>>>(h1, stats);
    bn_apply16<<<(NN * 8 + B - 1) / B, B, 0, stream>>>(h1, stats, g1, be1);

    // ---- layer 2 ----
    gather16<HID><<<(NN * 64 + B - 1) / B, B, 0, stream>>>(row_ptr, eidx, h1, agg);
    sage_mfma2<<<NN / 64, B, 0, stream>>>(h1, agg, row_ptr, bt2, b2, h2);
    bn_stats16<<<(NN + 511) / 512, B, 0, stream>>>(h2, stats + 128);

    // ---- fused BN2+ReLU+pool+head ----
    pool_out<<<(NG * 64 + B - 1) / B, B, 0, stream>>>(h2, stats + 128, g2, be2, gstart,
                                                      Wout, bout, (float*)d_out);
}